// Round 11
// baseline (1338.181 us; speedup 1.0000x reference)
//
#include <hip/hip_runtime.h>
#include <math.h>

#define BB 8
#define EE 2000
#define FF 6000
#define QQ 20
#define DD 256
#define NENT 400000
#define NWORD 60000
#define NNZ_ 96000
#define VNEG  (-1e11f)
#define VSMALL 1e-10f

typedef __attribute__((ext_vector_type(8))) short short8v;
typedef __attribute__((ext_vector_type(4))) short short4v;
typedef __attribute__((ext_vector_type(4))) float f32x4;

__device__ __forceinline__ unsigned short f2bf_rne(float x)
{
    unsigned u = __float_as_uint(x);
    u += 0x7FFFu + ((u >> 16) & 1u);
    return (unsigned short)(u >> 16);
}
__device__ __forceinline__ float bf2f(unsigned short h)
{
    return __uint_as_float((unsigned)h << 16);
}

// ---------------------------------------------------------------------------
// MFMA split-bf16 GEMM body. Block 128x128, 4 waves 2x2 (wave 64x64).
// ASPLIT: A pre-split bf16 hi/lo in global, staged as pure 16B copies.
// else  : A fp32 (+GATHER) staged with on-the-fly hi/lo split.
// hi*hi+hi*lo+lo*hi fp32 accum. Frag layout HW-verified (r5/r8).
//   DUALW : K=512, second half from A2 sidecars / W2 (scales folded in W)
//   BIASB : biasA indexed [(r/EE)*256+c] else [c];  RS: += rowscale[r]*bias2[c]
//   WRITEB: also emit bf16 hi/lo sidecar of the result
// M multiple of 128, N=256 (bx in {0,1}). W pre-split, ld 256.
// ---------------------------------------------------------------------------
template<int GATHER, int ASPLIT, int DUALW, int RELU, int RS, int BIASB, int WRITEB>
__device__ __forceinline__ void mgemm_body(
    const float* __restrict__ A1f, const int* __restrict__ idx,
    const short* __restrict__ A1h, const short* __restrict__ A1l,
    const short* __restrict__ A2h, const short* __restrict__ A2l,
    const short* __restrict__ W1h, const short* __restrict__ W1l,
    const short* __restrict__ W2h, const short* __restrict__ W2l,
    const float* __restrict__ biasA,
    const float* __restrict__ rowscale, const float* __restrict__ bias2,
    float* __restrict__ outF, short* __restrict__ outH, short* __restrict__ outL,
    int by, int bx, short* __restrict__ Ah, short* __restrict__ Al)
{
    const int tid = threadIdx.x;
    const int lane = tid & 63, wv = tid >> 6;
    const int wrow = wv >> 1, wcol = wv & 1;
    const int row0 = by * 128, col0 = bx * 128;

    const int sr = tid >> 1;
    const int sko = (tid & 1) << 5;
    const int grow = row0 + sr;
    const float* aRowF = nullptr;
    if (!ASPLIT) aRowF = GATHER ? A1f + (size_t)idx[grow] * 256 : A1f + (size_t)grow * 256;
    const size_t arow = (size_t)grow * 256;

    f32x4 acc[4][4];
    #pragma unroll
    for (int i = 0; i < 4; ++i)
        #pragma unroll
        for (int j = 0; j < 4; ++j) acc[i][j] = (f32x4){0.f, 0.f, 0.f, 0.f};

    const int nch = DUALW ? 8 : 4;
    for (int ch = 0; ch < nch; ++ch) {
        const bool hi2 = DUALW && (ch >= 4);
        const int kbase = (ch & 3) << 6;
        if (ASPLIT) {
            const short* __restrict__ sH = (hi2 ? A2h : A1h) + arow + kbase + sko;
            const short* __restrict__ sL = (hi2 ? A2l : A1l) + arow + kbase + sko;
            #pragma unroll
            for (int q = 0; q < 4; ++q) {
                const int kc = sko + (q << 3);
                short8v h = *(const short8v*)(sH + (q << 3));
                short8v l = *(const short8v*)(sL + (q << 3));
                const int tI = ((sr >> 4) << 1) + (kc >> 5);
                const int off = (tI << 9) + (((sr & 15) + (((kc >> 3) & 3) << 4)) << 3);
                *(short8v*)(Ah + off) = h;
                *(short8v*)(Al + off) = l;
            }
        } else {
            #pragma unroll
            for (int q = 0; q < 8; ++q) {
                const int kc = sko + (q << 2);
                float4 a = *(const float4*)(aRowF + kbase + kc);
                unsigned short h0 = f2bf_rne(a.x), h1 = f2bf_rne(a.y),
                               h2 = f2bf_rne(a.z), h3 = f2bf_rne(a.w);
                unsigned short l0 = f2bf_rne(a.x - bf2f(h0)), l1 = f2bf_rne(a.y - bf2f(h1)),
                               l2 = f2bf_rne(a.z - bf2f(h2)), l3 = f2bf_rne(a.w - bf2f(h3));
                const int tI = ((sr >> 4) << 1) + (kc >> 5);
                const int off = (tI << 9) + (((sr & 15) + (((kc >> 3) & 3) << 4)) << 3) + (kc & 7);
                *(short4v*)(Ah + off) = (short4v){(short)h0, (short)h1, (short)h2, (short)h3};
                *(short4v*)(Al + off) = (short4v){(short)l0, (short)l1, (short)l2, (short)l3};
            }
        }
        __syncthreads();
        const short* Wh = hi2 ? W2h : W1h;
        const short* Wl = hi2 ? W2l : W1l;
        #pragma unroll
        for (int ks = 0; ks < 2; ++ks) {
            const int kg = kbase + (ks << 5) + ((lane >> 4) << 3);
            short8v bh[4], bl[4];
            #pragma unroll
            for (int ct = 0; ct < 4; ++ct) {
                const int c = col0 + (wcol << 6) + (ct << 4) + (lane & 15);
                bh[ct] = *(const short8v*)(Wh + (size_t)c * 256 + kg);
                bl[ct] = *(const short8v*)(Wl + (size_t)c * 256 + kg);
            }
            #pragma unroll
            for (int rt = 0; rt < 4; ++rt) {
                const int tI = (((wrow << 2) + rt) << 1) + ks;
                const short8v avh = *(const short8v*)(Ah + (tI << 9) + (lane << 3));
                const short8v avl = *(const short8v*)(Al + (tI << 9) + (lane << 3));
                #pragma unroll
                for (int ct = 0; ct < 4; ++ct) {
                    acc[rt][ct] = __builtin_amdgcn_mfma_f32_16x16x32_bf16(avh, bh[ct], acc[rt][ct], 0, 0, 0);
                    acc[rt][ct] = __builtin_amdgcn_mfma_f32_16x16x32_bf16(avh, bl[ct], acc[rt][ct], 0, 0, 0);
                    acc[rt][ct] = __builtin_amdgcn_mfma_f32_16x16x32_bf16(avl, bh[ct], acc[rt][ct], 0, 0, 0);
                }
            }
        }
        __syncthreads();
    }
    #pragma unroll
    for (int rt = 0; rt < 4; ++rt) {
        const int rb = row0 + (wrow << 6) + (rt << 4) + ((lane >> 4) << 2);
        #pragma unroll
        for (int ct = 0; ct < 4; ++ct) {
            const int c = col0 + (wcol << 6) + (ct << 4) + (lane & 15);
            #pragma unroll
            for (int j = 0; j < 4; ++j) {
                const int r = rb + j;
                float v = acc[rt][ct][j];
                v += BIASB ? biasA[(size_t)(r / EE) * 256 + c] : biasA[c];
                if (RS) v += rowscale[r] * bias2[c];
                if (RELU) v = fmaxf(v, 0.f);
                outF[(size_t)r * 256 + c] = v;
                if (WRITEB) {
                    unsigned short h = f2bf_rne(v);
                    outH[(size_t)r * 256 + c] = (short)h;
                    outL[(size_t)r * 256 + c] = (short)f2bf_rne(v - bf2f(h));
                }
            }
        }
    }
}

// ---------------------------------------------------------------------------
// small per-batch bodies (run inside fused dispatches)
// ---------------------------------------------------------------------------
__device__ __forceinline__ void qlin_ebias_body(
    int b, int j, const float* __restrict__ qne, const float* __restrict__ q2eW,
    const float* __restrict__ q2eb, const float* __restrict__ e2eW,
    const float* __restrict__ e2eb, float* __restrict__ qlin,
    float* __restrict__ ebias, float* __restrict__ lds)
{
    float* xs = lds; float* qs = lds + 256;
    xs[j] = qne[b * DD + j];
    __syncthreads();
    float acc = q2eb[j];
    const float* wr = q2eW + (size_t)j * DD;
    #pragma unroll 4
    for (int k = 0; k < DD; ++k) acc += xs[k] * wr[k];
    qlin[b * DD + j] = acc;
    qs[j] = acc;
    __syncthreads();
    float acc2 = e2eb[j];
    const float* wr2 = e2eW + (size_t)j * 768 + 256;
    #pragma unroll 4
    for (int k = 0; k < DD; ++k) acc2 += qs[k] * wr2[k];
    ebias[b * DD + j] = acc2;
}

#define VCH 80
#define NCHK (EE / VCH)   // 25
__device__ __forceinline__ void qneupd_body(
    int b, int j, const float* __restrict__ vpartL, const float* __restrict__ vpartF,
    const float* __restrict__ vpartS, const float* __restrict__ qlinCur,
    const float* __restrict__ W, const float* __restrict__ bias,
    float* __restrict__ qne,
    const float* __restrict__ q2eWn, const float* __restrict__ q2ebn,
    const float* __restrict__ e2eWn, const float* __restrict__ e2ebn,
    float* __restrict__ qlinNext, float* __restrict__ ebiasNext,
    float* __restrict__ lds)
{
    float* s1 = lds; float* s2 = lds + 256; float* s3 = lds + 512;
    float* qn = lds + 768; float* qs = lds + 1024;
    float a1 = 0.f, a3 = 0.f, sp = 0.f;
    for (int ch = 0; ch < NCHK; ++ch) {
        int pi = ch * BB + b;
        a1 += vpartL[(size_t)pi * DD + j];
        a3 += vpartF[(size_t)pi * DD + j];
        sp += vpartS[pi];
    }
    s1[j] = a1; s2[j] = qlinCur[b * DD + j]; s3[j] = a3;
    __syncthreads();
    float acc = sp * bias[j];
    const float* wr = W + (size_t)j * 768;
    #pragma unroll 4
    for (int k = 0; k < DD; ++k)
        acc += s1[k] * wr[k] + sp * s2[k] * wr[256 + k] + 3.f * s3[k] * wr[512 + k];
    qne[b * DD + j] = acc;
    qn[j] = acc;
    __syncthreads();
    float aq = q2ebn[j];
    const float* wq = q2eWn + (size_t)j * DD;
    #pragma unroll 4
    for (int k = 0; k < DD; ++k) aq += qn[k] * wq[k];
    qlinNext[b * DD + j] = aq;
    qs[j] = aq;
    __syncthreads();
    float ae = e2ebn[j];
    const float* we = e2eWn + (size_t)j * 768 + 256;
    #pragma unroll 4
    for (int k = 0; k < DD; ++k) ae += qs[k] * we[k];
    ebiasNext[b * DD + j] = ae;
}

__device__ __forceinline__ void vreduce_body(
    int ch, int b, int k,
    const int* __restrict__ f2e_rp, const int* __restrict__ f2e_col,
    const float* __restrict__ f2e_vp, const float* __restrict__ e2fnrm,
    float* __restrict__ pr, const float* __restrict__ lee,
    const float* __restrict__ f2e, float* __restrict__ vpartL,
    float* __restrict__ vpartF, float* __restrict__ vpartS,
    float* __restrict__ lds)
{
    float* prs = lds; float* red = lds + 128;
    int e0 = ch * VCH;
    if (k < VCH) {
        int row = b * EE + e0 + k;
        float s = 0.f;
        for (int j = f2e_rp[row]; j < f2e_rp[row + 1]; ++j)
            s += f2e_vp[j] * e2fnrm[(size_t)b * FF + f2e_col[j]];
        float v = 0.8f * s + 0.2f * pr[row];
        pr[row] = v;
        prs[k] = v;
    }
    __syncthreads();
    float a1 = 0.f, a2 = 0.f;
    for (int e = 0; e < VCH; ++e) {
        float p = prs[e];
        size_t base = ((size_t)b * EE + e0 + e) * DD + k;
        a1 += p * lee[base];
        a2 += p * f2e[base];
    }
    int pi = ch * BB + b;
    vpartL[(size_t)pi * DD + k] = a1;
    vpartF[(size_t)pi * DD + k] = a2;
    float sp = 0.f;
    for (int e = k; e < VCH; e += 256) sp += prs[e];
    red[k] = sp; __syncthreads();
    for (int s = 128; s > 0; s >>= 1) {
        if (k < s) red[k] += red[k + s];
        __syncthreads();
    }
    if (k == 0) vpartS[pi] = red[0];
}

// ---------------------------------------------------------------------------
// embeddings (fp32 GATHER path, WRITEB) + initial qlin/ebias, one dispatch
// blocks 0..999: GEMMs (bx=blk&1, by=blk>>1; by<375 rel else ent); 1000..1007 qlin
// ---------------------------------------------------------------------------
__global__ __launch_bounds__(256, 2) void embed_pair_k(
    const float* __restrict__ rel_table, const int* __restrict__ kb_fact_rel,
    const short* __restrict__ W0h, const short* __restrict__ W0l,
    const float* __restrict__ rel_b, float* __restrict__ lfe,
    short* __restrict__ lfeH, short* __restrict__ lfeL,
    const float* __restrict__ ent_table, const int* __restrict__ local_entity,
    const short* __restrict__ W1h, const short* __restrict__ W1l,
    const float* __restrict__ ent_b, float* __restrict__ lee,
    short* __restrict__ leeH, short* __restrict__ leeL,
    const float* __restrict__ qne, const float* __restrict__ q2eW,
    const float* __restrict__ q2eb, const float* __restrict__ e2eW,
    const float* __restrict__ e2eb, float* __restrict__ qlin, float* __restrict__ ebias)
{
    __shared__ char ldsbuf[32768];
    int blk = blockIdx.x;
    if (blk < 1000) {
        short* Ah = (short*)ldsbuf; short* Al = Ah + 8192;
        int bx = blk & 1, by = blk >> 1;
        if (by < 375)
            mgemm_body<1, 0, 0, 0, 0, 0, 1>(rel_table, kb_fact_rel, nullptr, nullptr,
                nullptr, nullptr, W0h, W0l, nullptr, nullptr, rel_b, nullptr, nullptr,
                lfe, lfeH, lfeL, by, bx, Ah, Al);
        else
            mgemm_body<1, 0, 0, 0, 0, 0, 1>(ent_table, local_entity, nullptr, nullptr,
                nullptr, nullptr, W1h, W1l, nullptr, nullptr, ent_b, nullptr, nullptr,
                lee, leeH, leeL, by - 375, bx, Ah, Al);
    } else {
        qlin_ebias_body(blk - 1000, threadIdx.x, qne, q2eW, q2eb, e2eW, e2eb,
                        qlin, ebias, (float*)ldsbuf);
    }
}

// ---------------------------------------------------------------------------
// per-layer head/self GEMMs (+ optional prev-layer qneupd), one dispatch
// ---------------------------------------------------------------------------
template<int NQ>
__global__ __launch_bounds__(256, 2) void layer_pair_k(
    const short* __restrict__ leeH, const short* __restrict__ leeL,
    const short* __restrict__ lfeH, const short* __restrict__ lfeL,
    const short* __restrict__ WheadH, const short* __restrict__ WheadL,
    const short* __restrict__ WselfH, const short* __restrict__ WselfL,
    const float* __restrict__ headb, const float* __restrict__ selfb,
    float* __restrict__ bufC, float* __restrict__ e2fT,
    const float* __restrict__ vpartL, const float* __restrict__ vpartF,
    const float* __restrict__ vpartS, const float* __restrict__ qlinCur,
    const float* __restrict__ e2qW, const float* __restrict__ e2qb,
    float* __restrict__ qne,
    const float* __restrict__ q2eWn, const float* __restrict__ q2ebn,
    const float* __restrict__ e2eWn, const float* __restrict__ e2ebn,
    float* __restrict__ qlinNext, float* __restrict__ ebiasNext)
{
    __shared__ char ldsbuf[32768];
    int blk = blockIdx.x;
    if (blk < 1000) {
        short* Ah = (short*)ldsbuf; short* Al = Ah + 8192;
        int bx = blk & 1, by = blk >> 1;
        if (by < 125)
            mgemm_body<0, 1, 0, 0, 0, 0, 0>(nullptr, nullptr, leeH, leeL, nullptr, nullptr,
                WheadH, WheadL, nullptr, nullptr, headb, nullptr, nullptr,
                bufC, nullptr, nullptr, by, bx, Ah, Al);
        else
            mgemm_body<0, 1, 0, 0, 0, 0, 0>(nullptr, nullptr, lfeH, lfeL, nullptr, nullptr,
                WselfH, WselfL, nullptr, nullptr, selfb, nullptr, nullptr,
                e2fT, nullptr, nullptr, by - 125, bx, Ah, Al);
    } else if (NQ) {
        qneupd_body(blk - 1000, threadIdx.x, vpartL, vpartF, vpartS, qlinCur,
                    e2qW, e2qb, qne, q2eWn, q2ebn, e2eWn, e2ebn,
                    qlinNext, ebiasNext, (float*)ldsbuf);
    }
}

// ---------------------------------------------------------------------------
// f2eT GEMM (ASPLIT DUALW: A=lee/tmp sidecars), WRITEB
// ---------------------------------------------------------------------------
__global__ __launch_bounds__(256, 2) void f2et_k(
    const short* __restrict__ leeH, const short* __restrict__ leeL,
    const short* __restrict__ tmpH, const short* __restrict__ tmpL,
    const short* __restrict__ WselfH, const short* __restrict__ WselfL,
    const short* __restrict__ WtailH, const short* __restrict__ WtailL,
    const float* __restrict__ selfb, const float* __restrict__ degw,
    const float* __restrict__ tailb,
    float* __restrict__ f2eT, short* __restrict__ f2eH, short* __restrict__ f2eL)
{
    __shared__ char ldsbuf[32768];
    short* Ah = (short*)ldsbuf; short* Al = Ah + 8192;
    mgemm_body<0, 1, 1, 1, 1, 0, 1>(nullptr, nullptr, leeH, leeL, tmpH, tmpL,
        WselfH, WselfL, WtailH, WtailL, selfb, degw, tailb,
        f2eT, f2eH, f2eL, blockIdx.y, blockIdx.x, Ah, Al);
}

// ---------------------------------------------------------------------------
// lee2 GEMM + (optional) vreduce_pr, one dispatch
// blocks 0..249: lee2 GEMM; 250..449: vreduce (when DOV)
// ---------------------------------------------------------------------------
template<int DOV>
__global__ __launch_bounds__(256, 2) void tail_k(
    const short* __restrict__ leeH, const short* __restrict__ leeL,
    const short* __restrict__ f2eH, const short* __restrict__ f2eL,
    const short* __restrict__ WaH, const short* __restrict__ WaL,
    const short* __restrict__ WbH, const short* __restrict__ WbL,
    const float* __restrict__ ebias, float* __restrict__ lee2,
    short* __restrict__ lee2H, short* __restrict__ lee2L,
    const int* __restrict__ f2e_rp, const int* __restrict__ f2e_col,
    const float* __restrict__ f2e_vp, const float* __restrict__ e2fnrm,
    float* __restrict__ pr, const float* __restrict__ lee,
    const float* __restrict__ f2eT, float* __restrict__ vpartL,
    float* __restrict__ vpartF, float* __restrict__ vpartS)
{
    __shared__ char ldsbuf[32768];
    int blk = blockIdx.x;
    if (blk < 250) {
        short* Ah = (short*)ldsbuf; short* Al = Ah + 8192;
        mgemm_body<0, 1, 1, 1, 0, 1, 1>(nullptr, nullptr, leeH, leeL, f2eH, f2eL,
            WaH, WaL, WbH, WbL, ebias, nullptr, nullptr,
            lee2, lee2H, lee2L, blk >> 1, blk & 1, Ah, Al);
    } else if (DOV) {
        int v = blk - 250;
        vreduce_body(v >> 3, v & 7, threadIdx.x, f2e_rp, f2e_col, f2e_vp, e2fnrm,
                     pr, lee, f2eT, vpartL, vpartF, vpartS, (float*)ldsbuf);
    }
}

// ---------------------------------------------------------------------------
// weight pre-split: 17 matrices 256x256 -> bf16 hi/lo (3x folded into e2eB)
// ---------------------------------------------------------------------------
__global__ void wpack_k(const float* __restrict__ relW, const float* __restrict__ entW,
                        const float* __restrict__ headW, const float* __restrict__ tailW,
                        const float* __restrict__ selfW, const float* __restrict__ e2eW,
                        short* __restrict__ wh, short* __restrict__ wl)
{
    int id = blockIdx.x * 256 + threadIdx.x;
    if (id >= 17 * 65536) return;
    int m = id >> 16, e = id & 65535;
    float x;
    if (m == 0)       x = relW[e];
    else if (m == 1)  x = entW[e];
    else if (m < 5)   x = headW[(size_t)(m - 2) * 65536 + e];
    else if (m < 8)   x = tailW[(size_t)(m - 5) * 65536 + e];
    else if (m < 11)  x = selfW[(size_t)(m - 8) * 65536 + e];
    else if (m < 14)  x = e2eW[(size_t)(m - 11) * 196608 + (size_t)(e >> 8) * 768 + (e & 255)];
    else              x = 3.f * e2eW[(size_t)(m - 14) * 196608 + (size_t)(e >> 8) * 768 + 512 + (e & 255)];
    unsigned short h = f2bf_rne(x);
    wh[id] = (short)h;
    wl[id] = (short)f2bf_rne(x - bf2f(h));
}

// ---------------------------------------------------------------------------
// fp32 64x128 GEMM (only for the tiny Xg GEMM, N=1024)
// ---------------------------------------------------------------------------
__global__ __launch_bounds__(256, 4) void gemm3_k(
    const float* __restrict__ A1, const int* __restrict__ idx,
    const float* __restrict__ W1, int ldw1,
    const float* __restrict__ biasA,
    float* __restrict__ out, int M, int N)
{
    __shared__ float As[16][68];
    __shared__ float Bs[16][132];
    const int tid = threadIdx.x;
    const int row0 = blockIdx.y * 64, col0 = blockIdx.x * 128;
    const int tx = tid & 15, ty = tid >> 4;
    const int srA = tid >> 2, skA = (tid & 3) << 2;
    const int srB = tid >> 1, skB = (tid & 1) << 3;
    const int grA = row0 + srA;
    const bool rvalid = (grA < M);
    const float* aRow1 = nullptr;
    if (rvalid) aRow1 = A1 + (size_t)idx[grA] * 256;
    const float* wR1 = W1 + (size_t)(col0 + srB) * ldw1;

    float acc[4][8];
    #pragma unroll
    for (int i = 0; i < 4; ++i)
        #pragma unroll
        for (int j = 0; j < 8; ++j) acc[i][j] = 0.f;

    float4 a0, b0, b1;
    auto fetch = [&](int ch) {
        const int k0 = ch << 4;
        if (rvalid) a0 = *(const float4*)(aRow1 + k0 + skA);
        else        a0 = make_float4(0.f, 0.f, 0.f, 0.f);
        b0 = *(const float4*)(wR1 + k0 + skB);
        b1 = *(const float4*)(wR1 + k0 + skB + 4);
    };

    fetch(0);
    for (int ch = 0; ch < 16; ++ch) {
        As[skA + 0][srA] = a0.x; As[skA + 1][srA] = a0.y;
        As[skA + 2][srA] = a0.z; As[skA + 3][srA] = a0.w;
        Bs[skB + 0][srB] = b0.x; Bs[skB + 1][srB] = b0.y;
        Bs[skB + 2][srB] = b0.z; Bs[skB + 3][srB] = b0.w;
        Bs[skB + 4][srB] = b1.x; Bs[skB + 5][srB] = b1.y;
        Bs[skB + 6][srB] = b1.z; Bs[skB + 7][srB] = b1.w;
        __syncthreads();
        if (ch + 1 < 16) fetch(ch + 1);
        #pragma unroll
        for (int kk = 0; kk < 16; ++kk) {
            float av[4], bv[8];
            *(float4*)&av[0] = *(const float4*)&As[kk][ty << 2];
            *(float4*)&bv[0] = *(const float4*)&Bs[kk][tx << 2];
            *(float4*)&bv[4] = *(const float4*)&Bs[kk][(tx << 2) + 64];
            #pragma unroll
            for (int i = 0; i < 4; ++i)
                #pragma unroll
                for (int j = 0; j < 8; ++j) acc[i][j] += av[i] * bv[j];
        }
        __syncthreads();
    }
    #pragma unroll
    for (int i = 0; i < 4; ++i) {
        int r = row0 + (ty << 2) + i;
        if (r >= M) continue;
        float* orow = out + (size_t)r * N;
        #pragma unroll
        for (int jh = 0; jh < 2; ++jh) {
            const int c = col0 + (jh << 6) + (tx << 2);
            float4 v;
            v.x = acc[i][jh * 4 + 0] + biasA[c + 0];
            v.y = acc[i][jh * 4 + 1] + biasA[c + 1];
            v.z = acc[i][jh * 4 + 2] + biasA[c + 2];
            v.w = acc[i][jh * 4 + 3] + biasA[c + 3];
            *(float4*)(orow + c) = v;
        }
    }
}

// ---------------------------------------------------------------------------
// CSR build
// ---------------------------------------------------------------------------
__global__ void csr_count2_k(const int* __restrict__ idxA, int* __restrict__ cntA,
                             const int* __restrict__ idxB, int* __restrict__ cntB)
{
    int k = blockIdx.x * 256 + threadIdx.x;
    if (k >= NNZ_) return;
    if (blockIdx.y == 0) atomicAdd(&cntA[idxA[k] * FF + idxA[NNZ_ + k]], 1);
    else                 atomicAdd(&cntB[idxB[k] * EE + idxB[NNZ_ + k]], 1);
}

__global__ __launch_bounds__(1024) void scan2_k(
    const int* __restrict__ cntA, int* __restrict__ rpA, int* __restrict__ curA, int nA,
    const int* __restrict__ cntB, int* __restrict__ rpB, int* __restrict__ curB, int nB)
{
    const int* cnt = blockIdx.x ? cntB : cntA;
    int* rp  = blockIdx.x ? rpB  : rpA;
    int* cur = blockIdx.x ? curB : curA;
    int n    = blockIdx.x ? nB   : nA;
    __shared__ int sums[1024];
    int t = threadIdx.x;
    int chunk = (n + 1023) / 1024;
    int lo = t * chunk, hi = lo + chunk;
    if (lo > n) lo = n;
    if (hi > n) hi = n;
    int s = 0;
    for (int i = lo; i < hi; ++i) s += cnt[i];
    sums[t] = s;
    __syncthreads();
    for (int off = 1; off < 1024; off <<= 1) {
        int v = (t >= off) ? sums[t - off] : 0;
        __syncthreads();
        sums[t] += v;
        __syncthreads();
    }
    int run = (t == 0) ? 0 : sums[t - 1];
    for (int i = lo; i < hi; ++i) { rp[i] = run; cur[i] = run; run += cnt[i]; }
    if (hi == n) rp[n] = run;
}

__global__ void csr_fill2_k(
    const int* __restrict__ idxA, const float* __restrict__ valA,
    int* __restrict__ curA, int* __restrict__ colA, float* __restrict__ vpA,
    const int* __restrict__ idxB, const float* __restrict__ valB,
    int* __restrict__ curB, int* __restrict__ colB, float* __restrict__ vpB)
{
    int k = blockIdx.x * 256 + threadIdx.x;
    if (k >= NNZ_) return;
    if (blockIdx.y == 0) {
        int row = idxA[k] * FF + idxA[NNZ_ + k];
        int p = atomicAdd(&curA[row], 1);
        colA[p] = idxA[2 * NNZ_ + k];
        vpA[p] = valA[k];
    } else {
        int row = idxB[k] * EE + idxB[NNZ_ + k];
        int p = atomicAdd(&curB[row], 1);
        colB[p] = idxB[2 * NNZ_ + k];
        vpB[p] = valB[k];
    }
}

__global__ void degw_k(const int* __restrict__ rp, const float* __restrict__ vp,
                       float* __restrict__ degw, int n)
{
    int r = blockIdx.x * 256 + threadIdx.x;
    if (r >= n) return;
    float s = 0.f;
    for (int j = rp[r]; j < rp[r + 1]; ++j) s += vp[j];
    degw[r] = s;
}

// ---------------------------------------------------------------------------
// fused e2f gather (relu + norm; e2fnrm written)
// ---------------------------------------------------------------------------
__global__ __launch_bounds__(256) void gather_fused_e2f_k(
    const int* __restrict__ rowptr, const int* __restrict__ col,
    const float* __restrict__ valp, const float* __restrict__ headsrc,
    const float* __restrict__ pr, const float* __restrict__ sm,
    const float* __restrict__ Wtil, float* __restrict__ e2fnrm,
    float* __restrict__ dst, int nrows)
{
    int gid = blockIdx.x * 256 + threadIdx.x;
    int row = gid >> 6, lane = gid & 63;
    if (row >= nrows) return;
    int b = row / FF;
    const float* prb = pr + (size_t)b * EE;
    const float* smb = sm + (size_t)b * EE;
    float4* dp = (float4*)(dst + (size_t)row * DD + (lane << 2));
    float4 acc = *dp;
    float ns = 0.f;
    int j0 = rowptr[row], j1 = rowptr[row + 1];
    for (int j = j0; j < j1; ++j) {
        int c = col[j];
        float v = valp[j];
        float4 x = *(const float4*)(headsrc + ((size_t)b * EE + c) * DD + (lane << 2));
        acc.x += v * x.x; acc.y += v * x.y; acc.z += v * x.z; acc.w += v * x.w;
        ns += v * (prb[c] / fmaxf(smb[c], VSMALL));
    }
    float nrm = Wtil[row] * ns;
    if (lane == 0) e2fnrm[row] = nrm;
    acc.x = fmaxf(acc.x, 0.f) * nrm; acc.y = fmaxf(acc.y, 0.f) * nrm;
    acc.z = fmaxf(acc.z, 0.f) * nrm; acc.w = fmaxf(acc.w, 0.f) * nrm;
    *dp = acc;
}

// gather -> bf16 hi/lo sidecar only (tmp feeds only the tail GEMM)
__global__ __launch_bounds__(256) void gather_sum_bf_k(
    const int* __restrict__ rowptr, const int* __restrict__ col,
    const float* __restrict__ valp, const float* __restrict__ src,
    short* __restrict__ dh, short* __restrict__ dl, int nrows, int nrPerB, int ncs)
{
    int gid = blockIdx.x * 256 + threadIdx.x;
    int row = gid >> 6, lane = gid & 63;
    if (row >= nrows) return;
    int b = row / nrPerB;
    float4 acc = make_float4(0.f, 0.f, 0.f, 0.f);
    int j0 = rowptr[row], j1 = rowptr[row + 1];
    for (int j = j0; j < j1; ++j) {
        int c = col[j];
        float v = valp[j];
        float4 x = *(const float4*)(src + ((size_t)b * ncs + c) * DD + (lane << 2));
        acc.x += v * x.x; acc.y += v * x.y; acc.z += v * x.z; acc.w += v * x.w;
    }
    unsigned short h0 = f2bf_rne(acc.x), h1 = f2bf_rne(acc.y),
                   h2 = f2bf_rne(acc.z), h3 = f2bf_rne(acc.w);
    size_t o = (size_t)row * DD + (lane << 2);
    *(short4v*)(dh + o) = (short4v){(short)h0, (short)h1, (short)h2, (short)h3};
    *(short4v*)(dl + o) = (short4v){
        (short)f2bf_rne(acc.x - bf2f(h0)), (short)f2bf_rne(acc.y - bf2f(h1)),
        (short)f2bf_rne(acc.z - bf2f(h2)), (short)f2bf_rne(acc.w - bf2f(h3))};
}

// ---------------------------------------------------------------------------
// LSTM
// ---------------------------------------------------------------------------
__global__ void transpose_whh_k(const float* __restrict__ Whh, float* __restrict__ WhhT)
{
    int i = blockIdx.x * 256 + threadIdx.x;
    int k = i >> 10, j = i & 1023;
    WhhT[i] = Whh[(size_t)j * 256 + k];
}

__global__ __launch_bounds__(256) void lstm_k(
    const float* __restrict__ Xg, const float* __restrict__ WhhT,
    const float* __restrict__ bhh, float* __restrict__ qh, float* __restrict__ qne)
{
    __shared__ float h[DD];
    __shared__ float gs[4 * DD];
    const int b = blockIdx.x, t = threadIdx.x;
    h[t] = 0.f;
    float c = 0.f;
    const float4 bb4 = *(const float4*)(bhh + 4 * t);
    const float4* wt4 = (const float4*)WhhT + t;
    __syncthreads();
    for (int step = 0; step < QQ; ++step) {
        float a0 = 0.f, a1 = 0.f, a2 = 0.f, a3 = 0.f;
        #pragma unroll 16
        for (int k = 0; k < DD; ++k) {
            float4 w = wt4[k * 256];
            float hk = h[k];
            a0 += w.x * hk; a1 += w.y * hk; a2 += w.z * hk; a3 += w.w * hk;
        }
        float4 xg = *(const float4*)(Xg + ((size_t)b * QQ + step) * 1024 + 4 * t);
        float4 g4 = make_float4(a0 + xg.x + bb4.x, a1 + xg.y + bb4.y,
                                a2 + xg.z + bb4.z, a3 + xg.w + bb4.w);
        *(float4*)(gs + 4 * t) = g4;
        __syncthreads();
        float gi = gs[t], gf = gs[DD + t], gg = gs[2 * DD + t], go = gs[3 * DD + t];
        float si = 1.f / (1.f + expf(-gi));
        float sf = 1.f / (1.f + expf(-gf));
        float so = 1.f / (1.f + expf(-go));
        c = sf * c + si * tanhf(gg);
        float hh = so * tanhf(c);
        h[t] = hh;
        qh[((size_t)b * QQ + step) * DD + t] = hh;
        __syncthreads();
    }
    qne[(size_t)b * DD + t] = h[t];
}

// ---------------------------------------------------------------------------
// sim -> softmax -> Wt ; rowmax+Wtil ; e2f_softmax scatter
// ---------------------------------------------------------------------------
__global__ __launch_bounds__(256) void simwt_k(
    const float* __restrict__ qhid, const int* __restrict__ qtext,
    const float* __restrict__ lfe, float* __restrict__ Wt)
{
    __shared__ float qs[QQ * DD];
    __shared__ float qmn[QQ];
    const int b = blockIdx.y;
    const int f = blockIdx.x * 256 + threadIdx.x;
    for (int i = threadIdx.x; i < QQ * DD; i += 256) qs[i] = qhid[(size_t)b * QQ * DD + i];
    if (threadIdx.x < QQ)
        qmn[threadIdx.x] = (qtext[b * QQ + threadIdx.x] != NWORD) ? 0.f : VNEG;
    __syncthreads();
    if (f >= FF) return;
    float acc[QQ];
    #pragma unroll
    for (int q = 0; q < QQ; ++q) acc[q] = 0.f;
    const float* lr = lfe + ((size_t)b * FF + f) * DD;
    for (int d = 0; d < DD; d += 4) {
        float4 x = *(const float4*)(lr + d);
        #pragma unroll
        for (int q = 0; q < QQ; ++q) {
            float4 y = *(const float4*)&qs[q * DD + d];
            acc[q] += x.x * y.x + x.y * y.y + x.z * y.z + x.w * y.w;
        }
    }
    const float inv = 0.0625f;
    float pre[QQ], m = -INFINITY;
    #pragma unroll
    for (int q = 0; q < QQ; ++q) { pre[q] = acc[q] * inv + qmn[q]; m = fmaxf(m, pre[q]); }
    float s = 0.f;
    #pragma unroll
    for (int q = 0; q < QQ; ++q) s += expf(pre[q] - m);
    float wt = 0.f;
    #pragma unroll
    for (int q = 0; q < QQ; ++q) wt += (expf(pre[q] - m) / s) * (acc[q] * inv);
    Wt[(size_t)b * FF + f] = wt;
}

__global__ __launch_bounds__(256) void rowmax_wtil_k(
    const float* __restrict__ Wt, float* __restrict__ Wtil)
{
    __shared__ float red[256];
    int b = blockIdx.x, t = threadIdx.x;
    float m = -INFINITY;
    for (int f = t; f < FF; f += 256) m = fmaxf(m, Wt[b * FF + f]);
    red[t] = m; __syncthreads();
    for (int s = 128; s > 0; s >>= 1) {
        if (t < s) red[t] = fmaxf(red[t], red[t + s]);
        __syncthreads();
    }
    float mx = red[0];
    for (int f = t; f < FF; f += 256) Wtil[b * FF + f] = expf(Wt[b * FF + f] - mx);
}

__global__ void scatter_sm_k(const int* __restrict__ idx, const float* __restrict__ val,
                             const float* __restrict__ Wtil, float* __restrict__ dst)
{
    int k = blockIdx.x * 256 + threadIdx.x;
    if (k >= NNZ_) return;
    int b = idx[k], e = idx[2 * NNZ_ + k], f = idx[NNZ_ + k];
    atomicAdd(&dst[(size_t)b * EE + e], val[k] * Wtil[(size_t)b * FF + f]);
}

// ---------------------------------------------------------------------------
// epilogue: score + pred_dist + argmax + loss, fused
// ---------------------------------------------------------------------------
__global__ __launch_bounds__(256) void final2_k(
    const float* __restrict__ lee, const float* __restrict__ sw_,
    const float* __restrict__ sb, const int* __restrict__ local_entity,
    const float* __restrict__ ans, float* __restrict__ out, float* __restrict__ losspart)
{
    __shared__ float sw[DD];
    int b = blockIdx.x, t = threadIdx.x;
    sw[t] = sw_[t];
    __syncthreads();
    float sb0 = sb[0];
    float lsum = 0.f, bm = -INFINITY;
    int bi = EE;
    for (int e = t; e < EE; e += 256) {
        const float* a = lee + ((size_t)b * EE + e) * DD;
        float s = sb0;
        for (int k = 0; k < DD; k += 4) {
            float4 v = *(const float4*)(a + k);
            s += v.x * sw[k] + v.y * sw[k + 1] + v.z * sw[k + 2] + v.w * sw[k + 3];
        }
        float mask = (local_entity[b * EE + e] != NENT) ? 1.f : 0.f;
        float smv = s + (1.f - mask) * VNEG;
        float sig;
        if (smv >= 0.f) sig = 1.f / (1.f + expf(-smv));
        else { float es = expf(smv); sig = es / (1.f + es); }
        out[1 + BB + b * EE + e] = sig * mask;
        lsum += fmaxf(s, 0.f) - s * ans[b * EE + e] + log1pf(expf(-fabsf(s)));
        if (smv > bm) { bm = smv; bi = e; }
    }
    __shared__ float rv[256]; __shared__ int ri[256]; __shared__ float rl[256];
    rv[t] = bm; ri[t] = bi; rl[t] = lsum;
    __syncthreads();
    for (int s = 128; s > 0; s >>= 1) {
        if (t < s) {
            rl[t] += rl[t + s];
            if (rv[t + s] > rv[t] || (rv[t + s] == rv[t] && ri[t + s] < ri[t])) {
                rv[t] = rv[t + s]; ri[t] = ri[t + s];
            }
        }
        __syncthreads();
    }
    if (t == 0) { losspart[b] = rl[0]; out[1 + b] = (float)ri[0]; }
}

__global__ void loss_k(const float* __restrict__ losspart, float* __restrict__ out)
{
    if (threadIdx.x == 0) {
        float s = 0.f;
        for (int b = 0; b < BB; ++b) s += losspart[b];
        out[0] = s / (float)(BB * EE);
    }
}

// ---------------------------------------------------------------------------
extern "C" void kernel_launch(void* const* d_in, const int* in_sizes, int n_in,
                              void* d_out, int out_size, void* d_ws, size_t ws_size,
                              hipStream_t stream)
{
    (void)in_sizes; (void)n_in; (void)out_size; (void)ws_size;
    const int*   local_entity = (const int*)d_in[0];
    const float* q2e_adj      = (const float*)d_in[1];
    const int*   kb_fact_rel  = (const int*)d_in[2];
    const int*   query_text   = (const int*)d_in[3];
    const float* answer_dist  = (const float*)d_in[4];
    const int*   e2f_idx      = (const int*)d_in[5];
    const float* e2f_val      = (const float*)d_in[6];
    const int*   f2e_idx      = (const int*)d_in[7];
    const float* f2e_val      = (const float*)d_in[8];
    const float* entity_table = (const float*)d_in[9];
    const float* ent_W        = (const float*)d_in[10];
    const float* ent_b        = (const float*)d_in[11];
    const float* rel_table    = (const float*)d_in[12];
    const float* rel_W        = (const float*)d_in[13];
    const float* rel_b        = (const float*)d_in[14];
    const float* word_table   = (const float*)d_in[15];
    const float* Wih          = (const float*)d_in[16];
    const float* Whh          = (const float*)d_in[17];
    const float* bih          = (const float*)d_in[18];
    const float* bhh          = (const float*)d_in[19];
    const float* q2e_W        = (const float*)d_in[20];
    const float* q2e_b        = (const float*)d_in[21];
    const float* e2q_W        = (const float*)d_in[22];
    const float* e2q_b        = (const float*)d_in[23];
    const float* e2e_W        = (const float*)d_in[24];
    const float* e2e_b        = (const float*)d_in[25];
    const float* head_W       = (const float*)d_in[26];
    const float* head_b       = (const float*)d_in[27];
    const float* tail_W       = (const float*)d_in[28];
    const float* tail_b       = (const float*)d_in[29];
    const float* self_W       = (const float*)d_in[30];
    const float* self_b       = (const float*)d_in[31];
    const float* score_W      = (const float*)d_in[32];
    const float* score_b      = (const float*)d_in[33];

    const int NR1 = BB * FF;   // 48000
    const int NR2 = BB * EE;   // 16000

    float* ws = (float*)d_ws;
    size_t off = 0;
    auto alloc = [&](size_t n) { float* p = ws + off; off += n; return p; };
    auto salloc = [&](size_t nshorts) { short* p = (short*)(ws + off); off += (nshorts + 1) / 2; return p; };
    float* Xg      = alloc((size_t)BB * QQ * 1024);
    float* WhhT    = alloc((size_t)1024 * DD);
    float* qh      = alloc((size_t)BB * QQ * DD);
    float* qne     = alloc(BB * DD);
    float* lfe     = alloc((size_t)NR1 * DD);
    float* leeA    = alloc((size_t)NR2 * DD);
    float* leeB    = alloc((size_t)NR2 * DD);
    float* Wt      = alloc(BB * FF);
    float* Wtil    = alloc(BB * FF);
    float* e2fsm   = alloc(BB * EE);
    float* pr      = alloc(BB * EE);
    float* qlinA   = alloc(BB * DD);
    float* qlinB   = alloc(BB * DD);
    float* ebiasA  = alloc(BB * DD);
    float* ebiasB  = alloc(BB * DD);
    float* e2fnrm  = alloc(BB * FF);
    float* losspart= alloc(8);
    float* bufC    = alloc((size_t)NR2 * DD);
    float* e2fT    = alloc((size_t)NR1 * DD);
    float* f2eT    = alloc((size_t)NR2 * DD);
    float* vpartL  = alloc((size_t)NCHK * BB * DD);
    float* vpartF  = alloc((size_t)NCHK * BB * DD);
    float* vpartS  = alloc(NCHK * BB);
    float* degw2   = alloc(NR2);
    float* e2f_vp  = alloc(NNZ_);
    float* f2e_vp  = alloc(NNZ_);
    short* lfeH  = salloc((size_t)NR1 * DD);
    short* lfeL  = salloc((size_t)NR1 * DD);
    short* leeHA = salloc((size_t)NR2 * DD);
    short* leeLA = salloc((size_t)NR2 * DD);
    short* leeHB = salloc((size_t)NR2 * DD);
    short* leeLB = salloc((size_t)NR2 * DD);
    short* f2eH  = salloc((size_t)NR2 * DD);
    short* f2eL  = salloc((size_t)NR2 * DD);
    short* tmpH  = salloc((size_t)NR2 * DD);
    short* tmpL  = salloc((size_t)NR2 * DD);
    short* wbh   = salloc((size_t)17 * 65536);
    short* wbl   = salloc((size_t)17 * 65536);
    int* ib = (int*)(ws + off);
    size_t ioff = 0;
    auto ialloc = [&](size_t n) { int* p = ib + ioff; ioff += n; return p; };
    int* e2f_cnt = ialloc(NR1);
    int* e2f_rp  = ialloc(NR1 + 1);
    int* e2f_cur = ialloc(NR1);
    int* e2f_col = ialloc(NNZ_);
    int* f2e_cnt = ialloc(NR2);
    int* f2e_rp  = ialloc(NR2 + 1);
    int* f2e_cur = ialloc(NR2);
    int* f2e_col = ialloc(NNZ_);

    auto WH = [&](int m) { return wbh + (size_t)m * 65536; };
    auto WL = [&](int m) { return wbl + (size_t)m * 65536; };

    float* outp = (float*)d_out;
    const int SCB = (NNZ_ + 255) / 256;

    // ---- weight pre-split ----
    wpack_k<<<(17 * 65536) / 256, 256, 0, stream>>>(rel_W, ent_W, head_W, tail_W,
                                                    self_W, e2e_W, wbh, wbl);

    // ---- CSR builds ----
    hipMemsetAsync(e2f_cnt, 0, NR1 * sizeof(int), stream);
    hipMemsetAsync(f2e_cnt, 0, NR2 * sizeof(int), stream);
    csr_count2_k<<<dim3(SCB, 2), 256, 0, stream>>>(e2f_idx, e2f_cnt, f2e_idx, f2e_cnt);
    scan2_k<<<2, 1024, 0, stream>>>(e2f_cnt, e2f_rp, e2f_cur, NR1,
                                    f2e_cnt, f2e_rp, f2e_cur, NR2);
    csr_fill2_k<<<dim3(SCB, 2), 256, 0, stream>>>(
        e2f_idx, e2f_val, e2f_cur, e2f_col, e2f_vp,
        f2e_idx, f2e_val, f2e_cur, f2e_col, f2e_vp);
    degw_k<<<(NR2 + 255) / 256, 256, 0, stream>>>(f2e_rp, f2e_vp, degw2, NR2);

    // ---- LSTM ----
    gemm3_k<<<dim3(8, 3), 256, 0, stream>>>(
        word_table, query_text, Wih, 256, bih, Xg, BB * QQ, 1024);
    transpose_whh_k<<<1024, 256, 0, stream>>>(Whh, WhhT);
    lstm_k<<<BB, 256, 0, stream>>>(Xg, WhhT, bhh, qh, qne);

    // ---- embeddings (rel+ent, WRITEB) + initial qlin/ebias, ONE dispatch ----
    embed_pair_k<<<1008, 256, 0, stream>>>(
        rel_table, kb_fact_rel, WH(0), WL(0), rel_b, lfe, lfeH, lfeL,
        entity_table, local_entity, WH(1), WL(1), ent_b, leeA, leeHA, leeLA,
        qne, q2e_W, q2e_b, e2e_W, e2e_b, qlinA, ebiasA);

    // ---- attention -> W_tilde ----
    simwt_k<<<dim3((FF + 255) / 256, BB), 256, 0, stream>>>(qh, query_text, lfe, Wt);
    rowmax_wtil_k<<<BB, 256, 0, stream>>>(Wt, Wtil);

    // ---- e2f_softmax ----
    hipMemsetAsync(e2fsm, 0, BB * EE * sizeof(float), stream);
    scatter_sm_k<<<SCB, 256, 0, stream>>>(e2f_idx, e2f_val, Wtil, e2fsm);

    // ---- pagerank init ----
    hipMemcpyAsync(pr, q2e_adj, BB * EE * sizeof(float), hipMemcpyDeviceToDevice, stream);

    float* lee = leeA;   float* lee2 = leeB;
    short* leeH = leeHA; short* leeL = leeLA;
    short* leeH2 = leeHB; short* leeL2 = leeLB;
    float* qlinCur = qlinA;  float* qlinNxt = qlinB;
    float* ebiasCur = ebiasA; float* ebiasNxt = ebiasB;

    for (int i = 0; i < 3; ++i) {
        const float* headbi = head_b + i * DD;
        const float* tailbi = tail_b + i * DD;
        const float* selfbi = self_b + i * DD;

        // head(lee)+self(lfe) GEMMs (+ prev layer's qneupd when i>0)
        if (i == 0) {
            layer_pair_k<0><<<1000, 256, 0, stream>>>(
                leeH, leeL, lfeH, lfeL, WH(2 + i), WL(2 + i), WH(8 + i), WL(8 + i),
                headbi, selfbi, bufC, e2fT,
                nullptr, nullptr, nullptr, nullptr, nullptr, nullptr, nullptr,
                nullptr, nullptr, nullptr, nullptr, nullptr, nullptr);
        } else {
            const float* e2qWp = e2q_W + (size_t)(i - 1) * DD * 3 * DD;
            const float* e2qbp = e2q_b + (i - 1) * DD;
            const float* q2eWn = q2e_W + (size_t)i * DD * DD;
            const float* q2ebn = q2e_b + i * DD;
            const float* e2eWn = e2e_W + (size_t)i * DD * 3 * DD;
            const float* e2ebn = e2e_b + i * DD;
            layer_pair_k<1><<<1008, 256, 0, stream>>>(
                leeH, leeL, lfeH, lfeL, WH(2 + i), WL(2 + i), WH(8 + i), WL(8 + i),
                headbi, selfbi, bufC, e2fT,
                vpartL, vpartF, vpartS, qlinCur, e2qWp, e2qbp, qne,
                q2eWn, q2ebn, e2eWn, e2ebn, qlinNxt, ebiasNxt);
            { float* t = qlinCur; qlinCur = qlinNxt; qlinNxt = t; }
            { float* t = ebiasCur; ebiasCur = ebiasNxt; ebiasNxt = t; }
        }

        // e2fT = relu(e2fT + gather_e2f(bufC)) * nrm ; e2fnrm written
        gather_fused_e2f_k<<<(NR1 * 64) / 256, 256, 0, stream>>>(
            e2f_rp, e2f_col, e2f_vp, bufC, pr, e2fsm, Wtil, e2fnrm, e2fT, NR1);

        // tmp = gather_f2e(e2fT) -> bf16 sidecar
        gather_sum_bf_k<<<(NR2 * 64) / 256, 256, 0, stream>>>(
            f2e_rp, f2e_col, f2e_vp, e2fT, tmpH, tmpL, NR2, EE, FF);

        // f2eT = relu(lee@selfW^T + tmp@tailW^T + selfb + degw*tailb), +bf16
        f2et_k<<<dim3(2, 125), 256, 0, stream>>>(
            leeH, leeL, tmpH, tmpL, WH(8 + i), WL(8 + i), WH(5 + i), WL(5 + i),
            selfbi, degw2, tailbi, f2eT, f2eH, f2eL);

        // lee2 GEMM (+ vreduce_pr except last layer), one dispatch
        if (i < 2) {
            tail_k<1><<<450, 256, 0, stream>>>(
                leeH, leeL, f2eH, f2eL, WH(11 + i), WL(11 + i), WH(14 + i), WL(14 + i),
                ebiasCur, lee2, leeH2, leeL2,
                f2e_rp, f2e_col, f2e_vp, e2fnrm, pr, lee, f2eT,
                vpartL, vpartF, vpartS);
        } else {
            tail_k<0><<<250, 256, 0, stream>>>(
                leeH, leeL, f2eH, f2eL, WH(11 + i), WL(11 + i), WH(14 + i), WL(14 + i),
                ebiasCur, lee2, leeH2, leeL2,
                f2e_rp, f2e_col, f2e_vp, e2fnrm, pr, lee, f2eT,
                vpartL, vpartF, vpartS);
        }
        { float* t = lee; lee = lee2; lee2 = t; }
        { short* t = leeH; leeH = leeH2; leeH2 = t; }
        { short* t = leeL; leeL = leeL2; leeL2 = t; }
    }

    final2_k<<<BB, 256, 0, stream>>>(lee, score_W, score_b, local_entity,
                                     answer_dist, outp, losspart);
    loss_k<<<1, 64, 0, stream>>>(losspart, outp);
}

// Round 12
// 1258.598 us; speedup vs baseline: 1.0632x; 1.0632x over previous
//
#include <hip/hip_runtime.h>
#include <math.h>

#define BB 8
#define EE 2000
#define FF 6000
#define QQ 20
#define DD 256
#define NENT 400000
#define NWORD 60000
#define NNZ_ 96000
#define VNEG  (-1e11f)
#define VSMALL 1e-10f

typedef __attribute__((ext_vector_type(8))) short short8v;
typedef __attribute__((ext_vector_type(4))) short short4v;
typedef __attribute__((ext_vector_type(4))) float f32x4;

__device__ __forceinline__ unsigned short f2bf_rne(float x)
{
    unsigned u = __float_as_uint(x);
    u += 0x7FFFu + ((u >> 16) & 1u);
    return (unsigned short)(u >> 16);
}
__device__ __forceinline__ float bf2f(unsigned short h)
{
    return __uint_as_float((unsigned)h << 16);
}

// ---------------------------------------------------------------------------
// MFMA split-bf16 GEMM (r10 proven): out = act(A@W^T + bias).
// A fp32 in global; staged per 64-K chunk as hi/lo bf16 into frag-major LDS.
// Block 128x128, 4 waves 2x2 (wave 64x64). __launch_bounds__(256,2).
// ---------------------------------------------------------------------------
template<int GATHER, int DUALW, int RELU, int RS, int BIASB>
__device__ __forceinline__ void mgemm_body(
    const float* __restrict__ A1, const int* __restrict__ idx,
    const float* __restrict__ A2, float sA2,
    const short* __restrict__ W1h, const short* __restrict__ W1l,
    const short* __restrict__ W2h, const short* __restrict__ W2l,
    const float* __restrict__ biasA,
    const float* __restrict__ rowscale, const float* __restrict__ bias2,
    float* __restrict__ out, int by, int bx,
    short* __restrict__ Ah, short* __restrict__ Al)
{
    const int tid = threadIdx.x;
    const int lane = tid & 63, wv = tid >> 6;
    const int wrow = wv >> 1, wcol = wv & 1;
    const int row0 = by * 128, col0 = bx * 128;

    const int sr = tid >> 1;
    const int sko = (tid & 1) << 5;
    const int grow = row0 + sr;
    const float* aRow1 = GATHER ? A1 + (size_t)idx[grow] * 256 : A1 + (size_t)grow * 256;
    const float* aRow2 = DUALW ? A2 + (size_t)grow * 256 : nullptr;

    f32x4 acc[4][4];
    #pragma unroll
    for (int i = 0; i < 4; ++i)
        #pragma unroll
        for (int j = 0; j < 4; ++j) acc[i][j] = (f32x4){0.f, 0.f, 0.f, 0.f};

    const int nch = DUALW ? 8 : 4;
    for (int ch = 0; ch < nch; ++ch) {
        const bool hi2 = DUALW && (ch >= 4);
        const float* ar = hi2 ? aRow2 : aRow1;
        const int kbase = (ch & 3) << 6;
        #pragma unroll
        for (int q = 0; q < 8; ++q) {
            const int kc = sko + (q << 2);
            float4 a = *(const float4*)(ar + kbase + kc);
            if (DUALW && hi2) { a.x *= sA2; a.y *= sA2; a.z *= sA2; a.w *= sA2; }
            unsigned short h0 = f2bf_rne(a.x), h1 = f2bf_rne(a.y),
                           h2 = f2bf_rne(a.z), h3 = f2bf_rne(a.w);
            unsigned short l0 = f2bf_rne(a.x - bf2f(h0)), l1 = f2bf_rne(a.y - bf2f(h1)),
                           l2 = f2bf_rne(a.z - bf2f(h2)), l3 = f2bf_rne(a.w - bf2f(h3));
            const int tI = ((sr >> 4) << 1) + (kc >> 5);
            const int off = (tI << 9) + ((((sr & 15)) + (((kc >> 3) & 3) << 4)) << 3) + (kc & 7);
            *(short4v*)(Ah + off) = (short4v){(short)h0, (short)h1, (short)h2, (short)h3};
            *(short4v*)(Al + off) = (short4v){(short)l0, (short)l1, (short)l2, (short)l3};
        }
        __syncthreads();
        const short* Wh = hi2 ? W2h : W1h;
        const short* Wl = hi2 ? W2l : W1l;
        #pragma unroll
        for (int ks = 0; ks < 2; ++ks) {
            const int kg = kbase + (ks << 5) + ((lane >> 4) << 3);
            short8v bh[4], bl[4];
            #pragma unroll
            for (int ct = 0; ct < 4; ++ct) {
                const int c = col0 + (wcol << 6) + (ct << 4) + (lane & 15);
                bh[ct] = *(const short8v*)(Wh + (size_t)c * 256 + kg);
                bl[ct] = *(const short8v*)(Wl + (size_t)c * 256 + kg);
            }
            #pragma unroll
            for (int rt = 0; rt < 4; ++rt) {
                const int tI = (((wrow << 2) + rt) << 1) + ks;
                const short8v avh = *(const short8v*)(Ah + (tI << 9) + (lane << 3));
                const short8v avl = *(const short8v*)(Al + (tI << 9) + (lane << 3));
                #pragma unroll
                for (int ct = 0; ct < 4; ++ct) {
                    acc[rt][ct] = __builtin_amdgcn_mfma_f32_16x16x32_bf16(avh, bh[ct], acc[rt][ct], 0, 0, 0);
                    acc[rt][ct] = __builtin_amdgcn_mfma_f32_16x16x32_bf16(avh, bl[ct], acc[rt][ct], 0, 0, 0);
                    acc[rt][ct] = __builtin_amdgcn_mfma_f32_16x16x32_bf16(avl, bh[ct], acc[rt][ct], 0, 0, 0);
                }
            }
        }
        __syncthreads();
    }
    #pragma unroll
    for (int rt = 0; rt < 4; ++rt) {
        const int rb = row0 + (wrow << 6) + (rt << 4) + ((lane >> 4) << 2);
        #pragma unroll
        for (int ct = 0; ct < 4; ++ct) {
            const int c = col0 + (wcol << 6) + (ct << 4) + (lane & 15);
            #pragma unroll
            for (int j = 0; j < 4; ++j) {
                const int r = rb + j;
                float v = acc[rt][ct][j];
                v += BIASB ? biasA[(size_t)(r / EE) * 256 + c] : biasA[c];
                if (RS) v += rowscale[r] * bias2[c];
                if (RELU) v = fmaxf(v, 0.f);
                out[(size_t)r * 256 + c] = v;
            }
        }
    }
}

template<int GATHER, int DUALW, int RELU, int RS, int BIASB>
__global__ __launch_bounds__(256, 2) void mgemm_k(
    const float* __restrict__ A1, const int* __restrict__ idx,
    const float* __restrict__ A2, float sA2,
    const short* __restrict__ W1h, const short* __restrict__ W1l,
    const short* __restrict__ W2h, const short* __restrict__ W2l,
    const float* __restrict__ biasA,
    const float* __restrict__ rowscale, const float* __restrict__ bias2,
    float* __restrict__ out)
{
    __shared__ short Ah[16 * 512];
    __shared__ short Al[16 * 512];
    mgemm_body<GATHER, DUALW, RELU, RS, BIASB>(A1, idx, A2, sA2, W1h, W1l, W2h, W2l,
        biasA, rowscale, bias2, out, blockIdx.y, blockIdx.x, Ah, Al);
}

template<int GATHER>
__global__ __launch_bounds__(256, 2) void mgemm_pair_k(
    const float* __restrict__ Aa, const int* __restrict__ idxA,
    const short* __restrict__ Wah, const short* __restrict__ Wal,
    const float* __restrict__ ba, float* __restrict__ outa, int nya,
    const float* __restrict__ Ab, const int* __restrict__ idxB,
    const short* __restrict__ Wbh, const short* __restrict__ Wbl,
    const float* __restrict__ bb, float* __restrict__ outb)
{
    __shared__ short Ah[16 * 512];
    __shared__ short Al[16 * 512];
    const int by = blockIdx.y;
    if (by < nya)
        mgemm_body<GATHER, 0, 0, 0, 0>(Aa, idxA, nullptr, 1.f, Wah, Wal, nullptr, nullptr,
            ba, nullptr, nullptr, outa, by, blockIdx.x, Ah, Al);
    else
        mgemm_body<GATHER, 0, 0, 0, 0>(Ab, idxB, nullptr, 1.f, Wbh, Wbl, nullptr, nullptr,
            bb, nullptr, nullptr, outb, by - nya, blockIdx.x, Ah, Al);
}

// ---------------------------------------------------------------------------
// weight pre-split: 17 matrices of 256x256 -> bf16 hi/lo
// ---------------------------------------------------------------------------
__global__ void wpack_k(const float* __restrict__ relW, const float* __restrict__ entW,
                        const float* __restrict__ headW, const float* __restrict__ tailW,
                        const float* __restrict__ selfW, const float* __restrict__ e2eW,
                        short* __restrict__ wh, short* __restrict__ wl)
{
    int id = blockIdx.x * 256 + threadIdx.x;
    if (id >= 17 * 65536) return;
    int m = id >> 16, e = id & 65535;
    float x;
    if (m == 0)       x = relW[e];
    else if (m == 1)  x = entW[e];
    else if (m < 5)   x = headW[(size_t)(m - 2) * 65536 + e];
    else if (m < 8)   x = tailW[(size_t)(m - 5) * 65536 + e];
    else if (m < 11)  x = selfW[(size_t)(m - 8) * 65536 + e];
    else if (m < 14)  x = e2eW[(size_t)(m - 11) * 196608 + (size_t)(e >> 8) * 768 + (e & 255)];
    else              x = e2eW[(size_t)(m - 14) * 196608 + (size_t)(e >> 8) * 768 + 512 + (e & 255)];
    unsigned short h = f2bf_rne(x);
    wh[id] = (short)h;
    wl[id] = (short)f2bf_rne(x - bf2f(h));
}

// ---------------------------------------------------------------------------
// fp32 64x128 GEMM (only for the tiny Xg GEMM, N=1024)
// ---------------------------------------------------------------------------
template<int GATHER>
__global__ __launch_bounds__(256, 4) void gemm3_k(
    const float* __restrict__ A1, const int* __restrict__ idx,
    const float* __restrict__ W1, int ldw1,
    const float* __restrict__ biasA,
    float* __restrict__ out, int M, int N)
{
    __shared__ float As[16][68];
    __shared__ float Bs[16][132];
    const int tid = threadIdx.x;
    const int row0 = blockIdx.y * 64, col0 = blockIdx.x * 128;
    const int tx = tid & 15, ty = tid >> 4;
    const int srA = tid >> 2, skA = (tid & 3) << 2;
    const int srB = tid >> 1, skB = (tid & 1) << 3;
    const int grA = row0 + srA;
    const bool rvalid = (grA < M);
    const float* aRow1 = nullptr;
    if (rvalid) aRow1 = GATHER ? A1 + (size_t)idx[grA] * 256 : A1 + (size_t)grA * 256;
    const float* wR1 = W1 + (size_t)(col0 + srB) * ldw1;

    float acc[4][8];
    #pragma unroll
    for (int i = 0; i < 4; ++i)
        #pragma unroll
        for (int j = 0; j < 8; ++j) acc[i][j] = 0.f;

    float4 a0, b0, b1;
    auto fetch = [&](int ch) {
        const int k0 = ch << 4;
        if (rvalid) a0 = *(const float4*)(aRow1 + k0 + skA);
        else        a0 = make_float4(0.f, 0.f, 0.f, 0.f);
        b0 = *(const float4*)(wR1 + k0 + skB);
        b1 = *(const float4*)(wR1 + k0 + skB + 4);
    };

    fetch(0);
    for (int ch = 0; ch < 16; ++ch) {
        As[skA + 0][srA] = a0.x; As[skA + 1][srA] = a0.y;
        As[skA + 2][srA] = a0.z; As[skA + 3][srA] = a0.w;
        Bs[skB + 0][srB] = b0.x; Bs[skB + 1][srB] = b0.y;
        Bs[skB + 2][srB] = b0.z; Bs[skB + 3][srB] = b0.w;
        Bs[skB + 4][srB] = b1.x; Bs[skB + 5][srB] = b1.y;
        Bs[skB + 6][srB] = b1.z; Bs[skB + 7][srB] = b1.w;
        __syncthreads();
        if (ch + 1 < 16) fetch(ch + 1);
        #pragma unroll
        for (int kk = 0; kk < 16; ++kk) {
            float av[4], bv[8];
            *(float4*)&av[0] = *(const float4*)&As[kk][ty << 2];
            *(float4*)&bv[0] = *(const float4*)&Bs[kk][tx << 2];
            *(float4*)&bv[4] = *(const float4*)&Bs[kk][(tx << 2) + 64];
            #pragma unroll
            for (int i = 0; i < 4; ++i)
                #pragma unroll
                for (int j = 0; j < 8; ++j) acc[i][j] += av[i] * bv[j];
        }
        __syncthreads();
    }
    #pragma unroll
    for (int i = 0; i < 4; ++i) {
        int r = row0 + (ty << 2) + i;
        if (r >= M) continue;
        float* orow = out + (size_t)r * N;
        #pragma unroll
        for (int jh = 0; jh < 2; ++jh) {
            const int c = col0 + (jh << 6) + (tx << 2);
            float4 v;
            v.x = acc[i][jh * 4 + 0] + biasA[c + 0];
            v.y = acc[i][jh * 4 + 1] + biasA[c + 1];
            v.z = acc[i][jh * 4 + 2] + biasA[c + 2];
            v.w = acc[i][jh * 4 + 3] + biasA[c + 3];
            *(float4*)(orow + c) = v;
        }
    }
}

// ---------------------------------------------------------------------------
// CSR build
// ---------------------------------------------------------------------------
__global__ void csr_count2_k(const int* __restrict__ idxA, int* __restrict__ cntA,
                             const int* __restrict__ idxB, int* __restrict__ cntB)
{
    int k = blockIdx.x * 256 + threadIdx.x;
    if (k >= NNZ_) return;
    if (blockIdx.y == 0) atomicAdd(&cntA[idxA[k] * FF + idxA[NNZ_ + k]], 1);
    else                 atomicAdd(&cntB[idxB[k] * EE + idxB[NNZ_ + k]], 1);
}

__global__ __launch_bounds__(1024) void scan2_k(
    const int* __restrict__ cntA, int* __restrict__ rpA, int* __restrict__ curA, int nA,
    const int* __restrict__ cntB, int* __restrict__ rpB, int* __restrict__ curB, int nB)
{
    const int* cnt = blockIdx.x ? cntB : cntA;
    int* rp  = blockIdx.x ? rpB  : rpA;
    int* cur = blockIdx.x ? curB : curA;
    int n    = blockIdx.x ? nB   : nA;
    __shared__ int sums[1024];
    int t = threadIdx.x;
    int chunk = (n + 1023) / 1024;
    int lo = t * chunk, hi = lo + chunk;
    if (lo > n) lo = n;
    if (hi > n) hi = n;
    int s = 0;
    for (int i = lo; i < hi; ++i) s += cnt[i];
    sums[t] = s;
    __syncthreads();
    for (int off = 1; off < 1024; off <<= 1) {
        int v = (t >= off) ? sums[t - off] : 0;
        __syncthreads();
        sums[t] += v;
        __syncthreads();
    }
    int run = (t == 0) ? 0 : sums[t - 1];
    for (int i = lo; i < hi; ++i) { rp[i] = run; cur[i] = run; run += cnt[i]; }
    if (hi == n) rp[n] = run;
}

__global__ void csr_fill2_k(
    const int* __restrict__ idxA, const float* __restrict__ valA,
    int* __restrict__ curA, int* __restrict__ colA, float* __restrict__ vpA,
    const int* __restrict__ idxB, const float* __restrict__ valB,
    int* __restrict__ curB, int* __restrict__ colB, float* __restrict__ vpB)
{
    int k = blockIdx.x * 256 + threadIdx.x;
    if (k >= NNZ_) return;
    if (blockIdx.y == 0) {
        int row = idxA[k] * FF + idxA[NNZ_ + k];
        int p = atomicAdd(&curA[row], 1);
        colA[p] = idxA[2 * NNZ_ + k];
        vpA[p] = valA[k];
    } else {
        int row = idxB[k] * EE + idxB[NNZ_ + k];
        int p = atomicAdd(&curB[row], 1);
        colB[p] = idxB[2 * NNZ_ + k];
        vpB[p] = valB[k];
    }
}

__global__ void degw_k(const int* __restrict__ rp, const float* __restrict__ vp,
                       float* __restrict__ degw, int n)
{
    int r = blockIdx.x * 256 + threadIdx.x;
    if (r >= n) return;
    float s = 0.f;
    for (int j = rp[r]; j < rp[r + 1]; ++j) s += vp[j];
    degw[r] = s;
}

// ---------------------------------------------------------------------------
// fused e2f gather (relu + norm; e2fnrm written)
// ---------------------------------------------------------------------------
__global__ __launch_bounds__(256) void gather_fused_e2f_k(
    const int* __restrict__ rowptr, const int* __restrict__ col,
    const float* __restrict__ valp, const float* __restrict__ headsrc,
    const float* __restrict__ pr, const float* __restrict__ sm,
    const float* __restrict__ Wtil, float* __restrict__ e2fnrm,
    float* __restrict__ dst, int nrows)
{
    int gid = blockIdx.x * 256 + threadIdx.x;
    int row = gid >> 6, lane = gid & 63;
    if (row >= nrows) return;
    int b = row / FF;
    const float* prb = pr + (size_t)b * EE;
    const float* smb = sm + (size_t)b * EE;
    float4* dp = (float4*)(dst + (size_t)row * DD + (lane << 2));
    float4 acc = *dp;
    float ns = 0.f;
    int j0 = rowptr[row], j1 = rowptr[row + 1];
    for (int j = j0; j < j1; ++j) {
        int c = col[j];
        float v = valp[j];
        float4 x = *(const float4*)(headsrc + ((size_t)b * EE + c) * DD + (lane << 2));
        acc.x += v * x.x; acc.y += v * x.y; acc.z += v * x.z; acc.w += v * x.w;
        ns += v * (prb[c] / fmaxf(smb[c], VSMALL));
    }
    float nrm = Wtil[row] * ns;
    if (lane == 0) e2fnrm[row] = nrm;
    acc.x = fmaxf(acc.x, 0.f) * nrm; acc.y = fmaxf(acc.y, 0.f) * nrm;
    acc.z = fmaxf(acc.z, 0.f) * nrm; acc.w = fmaxf(acc.w, 0.f) * nrm;
    *dp = acc;
}

// dst[row] = sum val*src[b,c]  (pure gather, fp32 out)
__global__ __launch_bounds__(256) void gather_sum_k(
    const int* __restrict__ rowptr, const int* __restrict__ col,
    const float* __restrict__ valp, const float* __restrict__ src,
    float* __restrict__ dst, int nrows, int nrPerB, int ncs)
{
    int gid = blockIdx.x * 256 + threadIdx.x;
    int row = gid >> 6, lane = gid & 63;
    if (row >= nrows) return;
    int b = row / nrPerB;
    float4 acc = make_float4(0.f, 0.f, 0.f, 0.f);
    int j0 = rowptr[row], j1 = rowptr[row + 1];
    for (int j = j0; j < j1; ++j) {
        int c = col[j];
        float v = valp[j];
        float4 x = *(const float4*)(src + ((size_t)b * ncs + c) * DD + (lane << 2));
        acc.x += v * x.x; acc.y += v * x.y; acc.z += v * x.z; acc.w += v * x.w;
    }
    *(float4*)(dst + (size_t)row * DD + (lane << 2)) = acc;
}

// ---------------------------------------------------------------------------
// LSTM v2: 64 blocks (8 per batch), Whh slice LDS-cached, 1 grid barrier/step.
// Block (b,p): gate rows [p*128, p*128+128) of batch b. h/c replicated per
// block (identical fp32 ops -> deterministic). gbuf double-buffered so one
// barrier per step suffices. 64 blocks x 1 block/CU -> always co-resident.
// ---------------------------------------------------------------------------
#define LSTM_BLOCKS 64
__global__ __launch_bounds__(256, 1) void lstm2_k(
    const float* __restrict__ Xg, const float* __restrict__ Whh,
    const float* __restrict__ bhh, float* __restrict__ gbuf,
    unsigned* __restrict__ bar, float* __restrict__ qh, float* __restrict__ qne)
{
    __shared__ float wslice[128 * 257];   // padded: stride 257 -> conflict-free
    __shared__ float hbuf[256];
    __shared__ float cbuf[256];
    __shared__ float gpart[256];
    const int B = blockIdx.x;
    const int b = B >> 3, p = B & 7;
    const int t = threadIdx.x;
    // load 128-row Whh slice (contiguous 128KB) into padded LDS
    const float* wsrc = Whh + (size_t)p * 128 * 256;
    for (int i = t; i < 128 * 64; i += 256) {
        int row = i >> 6, q4 = (i & 63) << 2;
        float4 w = *(const float4*)(wsrc + (size_t)row * 256 + q4);
        float* d = &wslice[row * 257 + q4];
        d[0] = w.x; d[1] = w.y; d[2] = w.z; d[3] = w.w;
    }
    hbuf[t] = 0.f; cbuf[t] = 0.f;
    __syncthreads();

    unsigned* bar_cnt = bar;
    unsigned* bar_gen = bar + 1;

    for (int step = 0; step < QQ; ++step) {
        // gate partials: thread t -> row t&127, k-half t>>7
        {
            const int r = t & 127, half = t >> 7;
            const float* wr = &wslice[r * 257 + half * 128];
            const float* hb = &hbuf[half * 128];
            float acc = 0.f;
            #pragma unroll 8
            for (int k = 0; k < 128; ++k) acc += wr[k] * hb[k];
            gpart[t] = acc;
        }
        __syncthreads();
        if (t < 128) {
            const int gr = p * 128 + t;
            float g = bhh[gr] + Xg[((size_t)b * QQ + step) * 1024 + gr]
                    + gpart[t] + gpart[t + 128];
            gbuf[((size_t)(step & 1) * BB + b) * 1024 + gr] = g;
        }
        // grid barrier (device-scope)
        __syncthreads();
        if (t == 0) {
            __threadfence();
            const unsigned target = (unsigned)(step + 1) * LSTM_BLOCKS;
            unsigned old = atomicAdd(bar_cnt, 1u);
            if (old == target - 1u) {
                atomicExch(bar_gen, (unsigned)(step + 1));
            } else {
                while (atomicAdd(bar_gen, 0u) < (unsigned)(step + 1)) {}
            }
            __threadfence();
        }
        __syncthreads();
        // replicated h/c update (all blocks of batch b compute identically)
        {
            const float* g = gbuf + ((size_t)(step & 1) * BB + b) * 1024;
            float gi = g[t], gf = g[256 + t], gg = g[512 + t], go = g[768 + t];
            float si = 1.f / (1.f + expf(-gi));
            float sf = 1.f / (1.f + expf(-gf));
            float so = 1.f / (1.f + expf(-go));
            float c = sf * cbuf[t] + si * tanhf(gg);
            float hh = so * tanhf(c);
            cbuf[t] = c;
            hbuf[t] = hh;
            if (p == 0) qh[((size_t)b * QQ + step) * DD + t] = hh;
        }
        __syncthreads();
    }
    if (p == 0) qne[(size_t)b * DD + t] = hbuf[t];
}

// ---------------------------------------------------------------------------
// sim -> softmax -> Wt ; rowmax+Wtil ; e2f_softmax scatter
// ---------------------------------------------------------------------------
__global__ __launch_bounds__(256) void simwt_k(
    const float* __restrict__ qhid, const int* __restrict__ qtext,
    const float* __restrict__ lfe, float* __restrict__ Wt)
{
    __shared__ float qs[QQ * DD];
    __shared__ float qmn[QQ];
    const int b = blockIdx.y;
    const int f = blockIdx.x * 256 + threadIdx.x;
    for (int i = threadIdx.x; i < QQ * DD; i += 256) qs[i] = qhid[(size_t)b * QQ * DD + i];
    if (threadIdx.x < QQ)
        qmn[threadIdx.x] = (qtext[b * QQ + threadIdx.x] != NWORD) ? 0.f : VNEG;
    __syncthreads();
    if (f >= FF) return;
    float acc[QQ];
    #pragma unroll
    for (int q = 0; q < QQ; ++q) acc[q] = 0.f;
    const float* lr = lfe + ((size_t)b * FF + f) * DD;
    for (int d = 0; d < DD; d += 4) {
        float4 x = *(const float4*)(lr + d);
        #pragma unroll
        for (int q = 0; q < QQ; ++q) {
            float4 y = *(const float4*)&qs[q * DD + d];
            acc[q] += x.x * y.x + x.y * y.y + x.z * y.z + x.w * y.w;
        }
    }
    const float inv = 0.0625f;
    float pre[QQ], m = -INFINITY;
    #pragma unroll
    for (int q = 0; q < QQ; ++q) { pre[q] = acc[q] * inv + qmn[q]; m = fmaxf(m, pre[q]); }
    float s = 0.f;
    #pragma unroll
    for (int q = 0; q < QQ; ++q) s += expf(pre[q] - m);
    float wt = 0.f;
    #pragma unroll
    for (int q = 0; q < QQ; ++q) wt += (expf(pre[q] - m) / s) * (acc[q] * inv);
    Wt[(size_t)b * FF + f] = wt;
}

__global__ __launch_bounds__(256) void rowmax_wtil_k(
    const float* __restrict__ Wt, float* __restrict__ Wtil)
{
    __shared__ float red[256];
    int b = blockIdx.x, t = threadIdx.x;
    float m = -INFINITY;
    for (int f = t; f < FF; f += 256) m = fmaxf(m, Wt[b * FF + f]);
    red[t] = m; __syncthreads();
    for (int s = 128; s > 0; s >>= 1) {
        if (t < s) red[t] = fmaxf(red[t], red[t + s]);
        __syncthreads();
    }
    float mx = red[0];
    for (int f = t; f < FF; f += 256) Wtil[b * FF + f] = expf(Wt[b * FF + f] - mx);
}

__global__ void scatter_sm_k(const int* __restrict__ idx, const float* __restrict__ val,
                             const float* __restrict__ Wtil, float* __restrict__ dst)
{
    int k = blockIdx.x * 256 + threadIdx.x;
    if (k >= NNZ_) return;
    int b = idx[k], e = idx[2 * NNZ_ + k], f = idx[NNZ_ + k];
    atomicAdd(&dst[(size_t)b * EE + e], val[k] * Wtil[(size_t)b * FF + f]);
}

// ---------------------------------------------------------------------------
// initial qlin + ebias
// ---------------------------------------------------------------------------
__global__ __launch_bounds__(256) void qlin_ebias_k(
    const float* __restrict__ qne, const float* __restrict__ q2eW,
    const float* __restrict__ q2eb, const float* __restrict__ e2eW,
    const float* __restrict__ e2eb, float* __restrict__ qlin, float* __restrict__ ebias)
{
    __shared__ float xs[DD], qs[DD];
    int b = blockIdx.x, j = threadIdx.x;
    xs[j] = qne[b * DD + j];
    __syncthreads();
    float acc = q2eb[j];
    const float* wr = q2eW + (size_t)j * DD;
    #pragma unroll 4
    for (int k = 0; k < DD; ++k) acc += xs[k] * wr[k];
    qlin[b * DD + j] = acc;
    qs[j] = acc;
    __syncthreads();
    float acc2 = e2eb[j];
    const float* wr2 = e2eW + (size_t)j * 768 + 256;
    #pragma unroll 4
    for (int k = 0; k < DD; ++k) acc2 += qs[k] * wr2[k];
    ebias[b * DD + j] = acc2;
}

// ---------------------------------------------------------------------------
// fused pagerank update + vreduce partials
// ---------------------------------------------------------------------------
#define VCH 80
#define NCHK (EE / VCH)   // 25
__global__ __launch_bounds__(256) void vreduce_pr_k(
    const int* __restrict__ f2e_rp, const int* __restrict__ f2e_col,
    const float* __restrict__ f2e_vp, const float* __restrict__ e2fnrm,
    float* __restrict__ pr, const float* __restrict__ lee,
    const float* __restrict__ f2e, float* __restrict__ vpartL,
    float* __restrict__ vpartF, float* __restrict__ vpartS)
{
    int b = blockIdx.y, ch = blockIdx.x, k = threadIdx.x;
    int e0 = ch * VCH;
    __shared__ float prs[VCH];
    if (k < VCH) {
        int row = b * EE + e0 + k;
        float s = 0.f;
        for (int j = f2e_rp[row]; j < f2e_rp[row + 1]; ++j)
            s += f2e_vp[j] * e2fnrm[(size_t)b * FF + f2e_col[j]];
        float v = 0.8f * s + 0.2f * pr[row];
        pr[row] = v;
        prs[k] = v;
    }
    __syncthreads();
    float a1 = 0.f, a2 = 0.f;
    for (int e = 0; e < VCH; ++e) {
        float p = prs[e];
        size_t base = ((size_t)b * EE + e0 + e) * DD + k;
        a1 += p * lee[base];
        a2 += p * f2e[base];
    }
    int pi = ch * BB + b;
    vpartL[(size_t)pi * DD + k] = a1;
    vpartF[(size_t)pi * DD + k] = a2;
    float sp = 0.f;
    for (int e = k; e < VCH; e += 256) sp += prs[e];
    __shared__ float red[256];
    red[k] = sp; __syncthreads();
    for (int s = 128; s > 0; s >>= 1) {
        if (k < s) red[k] += red[k + s];
        __syncthreads();
    }
    if (k == 0) vpartS[pi] = red[0];
}

// ---------------------------------------------------------------------------
// qne update + next layer's qlin/ebias
// ---------------------------------------------------------------------------
__global__ __launch_bounds__(256) void qneupd_qlin_k(
    const float* __restrict__ vpartL, const float* __restrict__ vpartF,
    const float* __restrict__ vpartS, const float* __restrict__ qlinCur,
    const float* __restrict__ W, const float* __restrict__ bias,
    float* __restrict__ qne,
    const float* __restrict__ q2eWn, const float* __restrict__ q2ebn,
    const float* __restrict__ e2eWn, const float* __restrict__ e2ebn,
    float* __restrict__ qlinNext, float* __restrict__ ebiasNext, int hasNext)
{
    __shared__ float s1[DD], s2[DD], s3[DD], qn[DD], qs[DD];
    int b = blockIdx.x, j = threadIdx.x;
    float a1 = 0.f, a3 = 0.f, sp = 0.f;
    for (int ch = 0; ch < NCHK; ++ch) {
        int pi = ch * BB + b;
        a1 += vpartL[(size_t)pi * DD + j];
        a3 += vpartF[(size_t)pi * DD + j];
        sp += vpartS[pi];
    }
    s1[j] = a1; s2[j] = qlinCur[b * DD + j]; s3[j] = a3;
    __syncthreads();
    float acc = sp * bias[j];
    const float* wr = W + (size_t)j * 768;
    #pragma unroll 4
    for (int k = 0; k < DD; ++k)
        acc += s1[k] * wr[k] + sp * s2[k] * wr[256 + k] + 3.f * s3[k] * wr[512 + k];
    qne[b * DD + j] = acc;
    if (!hasNext) return;
    qn[j] = acc;
    __syncthreads();
    float aq = q2ebn[j];
    const float* wq = q2eWn + (size_t)j * DD;
    #pragma unroll 4
    for (int k = 0; k < DD; ++k) aq += qn[k] * wq[k];
    qlinNext[b * DD + j] = aq;
    qs[j] = aq;
    __syncthreads();
    float ae = e2ebn[j];
    const float* we = e2eWn + (size_t)j * 768 + 256;
    #pragma unroll 4
    for (int k = 0; k < DD; ++k) ae += qs[k] * we[k];
    ebiasNext[b * DD + j] = ae;
}

// ---------------------------------------------------------------------------
// epilogue: score + pred_dist + argmax + loss partial, fused
// ---------------------------------------------------------------------------
__global__ __launch_bounds__(256) void final2_k(
    const float* __restrict__ lee, const float* __restrict__ sw_,
    const float* __restrict__ sb, const int* __restrict__ local_entity,
    const float* __restrict__ ans, float* __restrict__ out, float* __restrict__ losspart)
{
    __shared__ float sw[DD];
    int b = blockIdx.x, t = threadIdx.x;
    sw[t] = sw_[t];
    __syncthreads();
    float sb0 = sb[0];
    float lsum = 0.f, bm = -INFINITY;
    int bi = EE;
    for (int e = t; e < EE; e += 256) {
        const float* a = lee + ((size_t)b * EE + e) * DD;
        float s = sb0;
        for (int k = 0; k < DD; k += 4) {
            float4 v = *(const float4*)(a + k);
            s += v.x * sw[k] + v.y * sw[k + 1] + v.z * sw[k + 2] + v.w * sw[k + 3];
        }
        float mask = (local_entity[b * EE + e] != NENT) ? 1.f : 0.f;
        float smv = s + (1.f - mask) * VNEG;
        float sig;
        if (smv >= 0.f) sig = 1.f / (1.f + expf(-smv));
        else { float es = expf(smv); sig = es / (1.f + es); }
        out[1 + BB + b * EE + e] = sig * mask;
        lsum += fmaxf(s, 0.f) - s * ans[b * EE + e] + log1pf(expf(-fabsf(s)));
        if (smv > bm) { bm = smv; bi = e; }
    }
    __shared__ float rv[256]; __shared__ int ri[256]; __shared__ float rl[256];
    rv[t] = bm; ri[t] = bi; rl[t] = lsum;
    __syncthreads();
    for (int s = 128; s > 0; s >>= 1) {
        if (t < s) {
            rl[t] += rl[t + s];
            if (rv[t + s] > rv[t] || (rv[t + s] == rv[t] && ri[t + s] < ri[t])) {
                rv[t] = rv[t + s]; ri[t] = ri[t + s];
            }
        }
        __syncthreads();
    }
    if (t == 0) { losspart[b] = rl[0]; out[1 + b] = (float)ri[0]; }
}

__global__ void loss_k(const float* __restrict__ losspart, float* __restrict__ out)
{
    if (threadIdx.x == 0) {
        float s = 0.f;
        for (int b = 0; b < BB; ++b) s += losspart[b];
        out[0] = s / (float)(BB * EE);
    }
}

// ---------------------------------------------------------------------------
extern "C" void kernel_launch(void* const* d_in, const int* in_sizes, int n_in,
                              void* d_out, int out_size, void* d_ws, size_t ws_size,
                              hipStream_t stream)
{
    (void)in_sizes; (void)n_in; (void)out_size; (void)ws_size;
    const int*   local_entity = (const int*)d_in[0];
    const float* q2e_adj      = (const float*)d_in[1];
    const int*   kb_fact_rel  = (const int*)d_in[2];
    const int*   query_text   = (const int*)d_in[3];
    const float* answer_dist  = (const float*)d_in[4];
    const int*   e2f_idx      = (const int*)d_in[5];
    const float* e2f_val      = (const float*)d_in[6];
    const int*   f2e_idx      = (const int*)d_in[7];
    const float* f2e_val      = (const float*)d_in[8];
    const float* entity_table = (const float*)d_in[9];
    const float* ent_W        = (const float*)d_in[10];
    const float* ent_b        = (const float*)d_in[11];
    const float* rel_table    = (const float*)d_in[12];
    const float* rel_W        = (const float*)d_in[13];
    const float* rel_b        = (const float*)d_in[14];
    const float* word_table   = (const float*)d_in[15];
    const float* Wih          = (const float*)d_in[16];
    const float* Whh          = (const float*)d_in[17];
    const float* bih          = (const float*)d_in[18];
    const float* bhh          = (const float*)d_in[19];
    const float* q2e_W        = (const float*)d_in[20];
    const float* q2e_b        = (const float*)d_in[21];
    const float* e2q_W        = (const float*)d_in[22];
    const float* e2q_b        = (const float*)d_in[23];
    const float* e2e_W        = (const float*)d_in[24];
    const float* e2e_b        = (const float*)d_in[25];
    const float* head_W       = (const float*)d_in[26];
    const float* head_b       = (const float*)d_in[27];
    const float* tail_W       = (const float*)d_in[28];
    const float* tail_b       = (const float*)d_in[29];
    const float* self_W       = (const float*)d_in[30];
    const float* self_b       = (const float*)d_in[31];
    const float* score_W      = (const float*)d_in[32];
    const float* score_b      = (const float*)d_in[33];

    const int NR1 = BB * FF;   // 48000
    const int NR2 = BB * EE;   // 16000

    float* ws = (float*)d_ws;
    size_t off = 0;
    auto alloc = [&](size_t n) { float* p = ws + off; off += n; return p; };
    auto salloc = [&](size_t nshorts) { short* p = (short*)(ws + off); off += (nshorts + 1) / 2; return p; };
    float* Xg      = alloc((size_t)BB * QQ * 1024);
    float* gbuf    = alloc((size_t)2 * BB * 1024);
    float* qh      = alloc((size_t)BB * QQ * DD);
    float* qne     = alloc(BB * DD);
    float* lfe     = alloc((size_t)NR1 * DD);
    float* leeA    = alloc((size_t)NR2 * DD);
    float* leeB    = alloc((size_t)NR2 * DD);
    float* Wt      = alloc(BB * FF);
    float* Wtil    = alloc(BB * FF);
    float* e2fsm   = alloc(BB * EE);
    float* pr      = alloc(BB * EE);
    float* qlinA   = alloc(BB * DD);
    float* qlinB   = alloc(BB * DD);
    float* ebiasA  = alloc(BB * DD);
    float* ebiasB  = alloc(BB * DD);
    float* e2fnrm  = alloc(BB * FF);
    float* losspart= alloc(8);
    float* bufC    = alloc((size_t)NR2 * DD);
    float* e2fT    = alloc((size_t)NR1 * DD);
    float* f2eT    = alloc((size_t)NR2 * DD);
    float* tmp     = alloc((size_t)NR2 * DD);
    float* vpartL  = alloc((size_t)NCHK * BB * DD);
    float* vpartF  = alloc((size_t)NCHK * BB * DD);
    float* vpartS  = alloc(NCHK * BB);
    float* degw2   = alloc(NR2);
    float* e2f_vp  = alloc(NNZ_);
    float* f2e_vp  = alloc(NNZ_);
    short* wbh     = salloc((size_t)17 * 65536);
    short* wbl     = salloc((size_t)17 * 65536);
    int* ib = (int*)(ws + off);
    size_t ioff = 0;
    auto ialloc = [&](size_t n) { int* p = ib + ioff; ioff += n; return p; };
    int* e2f_cnt = ialloc(NR1);
    int* e2f_rp  = ialloc(NR1 + 1);
    int* e2f_cur = ialloc(NR1);
    int* e2f_col = ialloc(NNZ_);
    int* f2e_cnt = ialloc(NR2);
    int* f2e_rp  = ialloc(NR2 + 1);
    int* f2e_cur = ialloc(NR2);
    int* f2e_col = ialloc(NNZ_);
    unsigned* bar = (unsigned*)ialloc(2);

    auto WH = [&](int m) { return wbh + (size_t)m * 65536; };
    auto WL = [&](int m) { return wbl + (size_t)m * 65536; };

    float* outp = (float*)d_out;
    const int SCB = (NNZ_ + 255) / 256;

    // ---- weight pre-split ----
    wpack_k<<<(17 * 65536) / 256, 256, 0, stream>>>(rel_W, ent_W, head_W, tail_W,
                                                    self_W, e2e_W, wbh, wbl);

    // ---- CSR builds ----
    hipMemsetAsync(e2f_cnt, 0, NR1 * sizeof(int), stream);
    hipMemsetAsync(f2e_cnt, 0, NR2 * sizeof(int), stream);
    csr_count2_k<<<dim3(SCB, 2), 256, 0, stream>>>(e2f_idx, e2f_cnt, f2e_idx, f2e_cnt);
    scan2_k<<<2, 1024, 0, stream>>>(e2f_cnt, e2f_rp, e2f_cur, NR1,
                                    f2e_cnt, f2e_rp, f2e_cur, NR2);
    csr_fill2_k<<<dim3(SCB, 2), 256, 0, stream>>>(
        e2f_idx, e2f_val, e2f_cur, e2f_col, e2f_vp,
        f2e_idx, f2e_val, f2e_cur, f2e_col, f2e_vp);
    degw_k<<<(NR2 + 255) / 256, 256, 0, stream>>>(f2e_rp, f2e_vp, degw2, NR2);

    // ---- LSTM (Xg GEMM + 64-block LDS-cached recurrence) ----
    gemm3_k<1><<<dim3(8, 3), 256, 0, stream>>>(
        word_table, query_text, Wih, 256, bih, Xg, BB * QQ, 1024);
    hipMemsetAsync(bar, 0, 2 * sizeof(unsigned), stream);
    lstm2_k<<<LSTM_BLOCKS, 256, 0, stream>>>(Xg, Whh, bhh, gbuf, bar, qh, qne);

    // ---- embeddings: rel + ent gathered GEMMs, ONE MFMA dispatch ----
    mgemm_pair_k<1><<<dim3(2, 375 + 125), 256, 0, stream>>>(
        rel_table, kb_fact_rel, WH(0), WL(0), rel_b, lfe, 375,
        entity_table, local_entity, WH(1), WL(1), ent_b, leeA);

    // ---- attention -> W_tilde ----
    simwt_k<<<dim3((FF + 255) / 256, BB), 256, 0, stream>>>(qh, query_text, lfe, Wt);
    rowmax_wtil_k<<<BB, 256, 0, stream>>>(Wt, Wtil);

    // ---- e2f_softmax ----
    hipMemsetAsync(e2fsm, 0, BB * EE * sizeof(float), stream);
    scatter_sm_k<<<SCB, 256, 0, stream>>>(e2f_idx, e2f_val, Wtil, e2fsm);

    // ---- pagerank init + initial qlin/ebias ----
    hipMemcpyAsync(pr, q2e_adj, BB * EE * sizeof(float), hipMemcpyDeviceToDevice, stream);
    qlin_ebias_k<<<BB, 256, 0, stream>>>(qne, q2e_W, q2e_b, e2e_W, e2e_b, qlinA, ebiasA);

    float* lee = leeA;   float* lee2 = leeB;
    float* qlinCur = qlinA;  float* qlinNxt = qlinB;
    float* ebiasCur = ebiasA; float* ebiasNxt = ebiasB;

    for (int i = 0; i < 3; ++i) {
        const float* e2qWi  = e2q_W  + (size_t)i * DD * 3 * DD;
        const float* e2qbi  = e2q_b  + i * DD;
        const float* headbi = head_b + i * DD;
        const float* tailbi = tail_b + i * DD;
        const float* selfbi = self_b + i * DD;

        // head(lee) -> bufC  AND  self(lfe) -> e2fT, one MFMA dispatch
        mgemm_pair_k<0><<<dim3(2, 125 + 375), 256, 0, stream>>>(
            lee, nullptr, WH(2 + i), WL(2 + i), headbi, bufC, 125,
            lfe, nullptr, WH(8 + i), WL(8 + i), selfbi, e2fT);

        // e2fT = relu(e2fT + gather_e2f(bufC)) * nrm ; e2fnrm written
        gather_fused_e2f_k<<<(NR1 * 64) / 256, 256, 0, stream>>>(
            e2f_rp, e2f_col, e2f_vp, bufC, pr, e2fsm, Wtil, e2fnrm, e2fT, NR1);

        // tmp = gather_f2e(e2fT)
        gather_sum_k<<<(NR2 * 64) / 256, 256, 0, stream>>>(
            f2e_rp, f2e_col, f2e_vp, e2fT, tmp, NR2, EE, FF);

        // f2eT = relu(lee@selfW^T + tmp@tailW^T + selfb + degw*tailb)
        mgemm_k<0, 1, 1, 1, 0><<<dim3(2, 125), 256, 0, stream>>>(
            lee, nullptr, tmp, 1.f, WH(8 + i), WL(8 + i), WH(5 + i), WL(5 + i),
            selfbi, degw2, tailbi, f2eT);

        // pagerank update + vreduce partials (fused)
        vreduce_pr_k<<<dim3(NCHK, BB), 256, 0, stream>>>(
            f2e_rp, f2e_col, f2e_vp, e2fnrm, pr, lee, f2eT, vpartL, vpartF, vpartS);

        // qne update + next layer's qlin/ebias
        int hasNext = (i < 2) ? 1 : 0;
        const float* q2eWn = q2e_W + (size_t)(i + 1) * DD * DD * (hasNext ? 1 : 0);
        const float* q2ebn = q2e_b + (i + 1) * DD * (hasNext ? 1 : 0);
        const float* e2eWn = e2e_W + (size_t)(i + 1) * DD * 3 * DD * (hasNext ? 1 : 0);
        const float* e2ebn = e2e_b + (i + 1) * DD * (hasNext ? 1 : 0);
        qneupd_qlin_k<<<BB, 256, 0, stream>>>(
            vpartL, vpartF, vpartS, qlinCur, e2qWi, e2qbi, qne,
            q2eWn, q2ebn, e2eWn, e2ebn, qlinNxt, ebiasNxt, hasNext);

        // lee2 = relu(lee@e2eA^T + 3*f2eT@e2eB^T + ebias[b])
        mgemm_k<0, 1, 1, 0, 1><<<dim3(2, 125), 256, 0, stream>>>(
            lee, nullptr, f2eT, 3.f, WH(11 + i), WL(11 + i), WH(14 + i), WL(14 + i),
            ebiasCur, nullptr, nullptr, lee2);
        { float* t = lee; lee = lee2; lee2 = t; }
        { float* t = qlinCur; qlinCur = qlinNxt; qlinNxt = t; }
        { float* t = ebiasCur; ebiasCur = ebiasNxt; ebiasNxt = t; }
    }

    final2_k<<<BB, 256, 0, stream>>>(lee, score_W, score_b, local_entity,
                                     answer_dist, outp, losspart);
    loss_k<<<1, 64, 0, stream>>>(losspart, outp);
}

// Round 14
// 1124.053 us; speedup vs baseline: 1.1905x; 1.1197x over previous
//
#include <hip/hip_runtime.h>
#include <math.h>

#define BB 8
#define EE 2000
#define FF 6000
#define QQ 20
#define DD 256
#define NENT 400000
#define NWORD 60000
#define NNZ_ 96000
#define VNEG  (-1e11f)
#define VSMALL 1e-10f

typedef __attribute__((ext_vector_type(8))) short short8v;
typedef __attribute__((ext_vector_type(4))) short short4v;
typedef __attribute__((ext_vector_type(4))) float f32x4;

__device__ __forceinline__ unsigned short f2bf_rne(float x)
{
    unsigned u = __float_as_uint(x);
    u += 0x7FFFu + ((u >> 16) & 1u);
    return (unsigned short)(u >> 16);
}
__device__ __forceinline__ float bf2f(unsigned short h)
{
    return __uint_as_float((unsigned)h << 16);
}

// ---------------------------------------------------------------------------
// MFMA split-bf16 GEMM (r10 proven): out = act(A@W^T + bias).
// A fp32 in global; staged per 64-K chunk as hi/lo bf16 into frag-major LDS.
// Block 128x128, 4 waves 2x2 (wave 64x64). __launch_bounds__(256,2).
// ---------------------------------------------------------------------------
template<int GATHER, int DUALW, int RELU, int RS, int BIASB>
__device__ __forceinline__ void mgemm_body(
    const float* __restrict__ A1, const int* __restrict__ idx,
    const float* __restrict__ A2, float sA2,
    const short* __restrict__ W1h, const short* __restrict__ W1l,
    const short* __restrict__ W2h, const short* __restrict__ W2l,
    const float* __restrict__ biasA,
    const float* __restrict__ rowscale, const float* __restrict__ bias2,
    float* __restrict__ out, int by, int bx,
    short* __restrict__ Ah, short* __restrict__ Al)
{
    const int tid = threadIdx.x;
    const int lane = tid & 63, wv = tid >> 6;
    const int wrow = wv >> 1, wcol = wv & 1;
    const int row0 = by * 128, col0 = bx * 128;

    const int sr = tid >> 1;
    const int sko = (tid & 1) << 5;
    const int grow = row0 + sr;
    const float* aRow1 = GATHER ? A1 + (size_t)idx[grow] * 256 : A1 + (size_t)grow * 256;
    const float* aRow2 = DUALW ? A2 + (size_t)grow * 256 : nullptr;

    f32x4 acc[4][4];
    #pragma unroll
    for (int i = 0; i < 4; ++i)
        #pragma unroll
        for (int j = 0; j < 4; ++j) acc[i][j] = (f32x4){0.f, 0.f, 0.f, 0.f};

    const int nch = DUALW ? 8 : 4;
    for (int ch = 0; ch < nch; ++ch) {
        const bool hi2 = DUALW && (ch >= 4);
        const float* ar = hi2 ? aRow2 : aRow1;
        const int kbase = (ch & 3) << 6;
        #pragma unroll
        for (int q = 0; q < 8; ++q) {
            const int kc = sko + (q << 2);
            float4 a = *(const float4*)(ar + kbase + kc);
            if (DUALW && hi2) { a.x *= sA2; a.y *= sA2; a.z *= sA2; a.w *= sA2; }
            unsigned short h0 = f2bf_rne(a.x), h1 = f2bf_rne(a.y),
                           h2 = f2bf_rne(a.z), h3 = f2bf_rne(a.w);
            unsigned short l0 = f2bf_rne(a.x - bf2f(h0)), l1 = f2bf_rne(a.y - bf2f(h1)),
                           l2 = f2bf_rne(a.z - bf2f(h2)), l3 = f2bf_rne(a.w - bf2f(h3));
            const int tI = ((sr >> 4) << 1) + (kc >> 5);
            const int off = (tI << 9) + ((((sr & 15)) + (((kc >> 3) & 3) << 4)) << 3) + (kc & 7);
            *(short4v*)(Ah + off) = (short4v){(short)h0, (short)h1, (short)h2, (short)h3};
            *(short4v*)(Al + off) = (short4v){(short)l0, (short)l1, (short)l2, (short)l3};
        }
        __syncthreads();
        const short* Wh = hi2 ? W2h : W1h;
        const short* Wl = hi2 ? W2l : W1l;
        #pragma unroll
        for (int ks = 0; ks < 2; ++ks) {
            const int kg = kbase + (ks << 5) + ((lane >> 4) << 3);
            short8v bh[4], bl[4];
            #pragma unroll
            for (int ct = 0; ct < 4; ++ct) {
                const int c = col0 + (wcol << 6) + (ct << 4) + (lane & 15);
                bh[ct] = *(const short8v*)(Wh + (size_t)c * 256 + kg);
                bl[ct] = *(const short8v*)(Wl + (size_t)c * 256 + kg);
            }
            #pragma unroll
            for (int rt = 0; rt < 4; ++rt) {
                const int tI = (((wrow << 2) + rt) << 1) + ks;
                const short8v avh = *(const short8v*)(Ah + (tI << 9) + (lane << 3));
                const short8v avl = *(const short8v*)(Al + (tI << 9) + (lane << 3));
                #pragma unroll
                for (int ct = 0; ct < 4; ++ct) {
                    acc[rt][ct] = __builtin_amdgcn_mfma_f32_16x16x32_bf16(avh, bh[ct], acc[rt][ct], 0, 0, 0);
                    acc[rt][ct] = __builtin_amdgcn_mfma_f32_16x16x32_bf16(avh, bl[ct], acc[rt][ct], 0, 0, 0);
                    acc[rt][ct] = __builtin_amdgcn_mfma_f32_16x16x32_bf16(avl, bh[ct], acc[rt][ct], 0, 0, 0);
                }
            }
        }
        __syncthreads();
    }
    #pragma unroll
    for (int rt = 0; rt < 4; ++rt) {
        const int rb = row0 + (wrow << 6) + (rt << 4) + ((lane >> 4) << 2);
        #pragma unroll
        for (int ct = 0; ct < 4; ++ct) {
            const int c = col0 + (wcol << 6) + (ct << 4) + (lane & 15);
            #pragma unroll
            for (int j = 0; j < 4; ++j) {
                const int r = rb + j;
                float v = acc[rt][ct][j];
                v += BIASB ? biasA[(size_t)(r / EE) * 256 + c] : biasA[c];
                if (RS) v += rowscale[r] * bias2[c];
                if (RELU) v = fmaxf(v, 0.f);
                out[(size_t)r * 256 + c] = v;
            }
        }
    }
}

template<int GATHER, int DUALW, int RELU, int RS, int BIASB>
__global__ __launch_bounds__(256, 2) void mgemm_k(
    const float* __restrict__ A1, const int* __restrict__ idx,
    const float* __restrict__ A2, float sA2,
    const short* __restrict__ W1h, const short* __restrict__ W1l,
    const short* __restrict__ W2h, const short* __restrict__ W2l,
    const float* __restrict__ biasA,
    const float* __restrict__ rowscale, const float* __restrict__ bias2,
    float* __restrict__ out)
{
    __shared__ short Ah[16 * 512];
    __shared__ short Al[16 * 512];
    mgemm_body<GATHER, DUALW, RELU, RS, BIASB>(A1, idx, A2, sA2, W1h, W1l, W2h, W2l,
        biasA, rowscale, bias2, out, blockIdx.y, blockIdx.x, Ah, Al);
}

template<int GATHER>
__global__ __launch_bounds__(256, 2) void mgemm_pair_k(
    const float* __restrict__ Aa, const int* __restrict__ idxA,
    const short* __restrict__ Wah, const short* __restrict__ Wal,
    const float* __restrict__ ba, float* __restrict__ outa, int nya,
    const float* __restrict__ Ab, const int* __restrict__ idxB,
    const short* __restrict__ Wbh, const short* __restrict__ Wbl,
    const float* __restrict__ bb, float* __restrict__ outb)
{
    __shared__ short Ah[16 * 512];
    __shared__ short Al[16 * 512];
    const int by = blockIdx.y;
    if (by < nya)
        mgemm_body<GATHER, 0, 0, 0, 0>(Aa, idxA, nullptr, 1.f, Wah, Wal, nullptr, nullptr,
            ba, nullptr, nullptr, outa, by, blockIdx.x, Ah, Al);
    else
        mgemm_body<GATHER, 0, 0, 0, 0>(Ab, idxB, nullptr, 1.f, Wbh, Wbl, nullptr, nullptr,
            bb, nullptr, nullptr, outb, by - nya, blockIdx.x, Ah, Al);
}

// ---------------------------------------------------------------------------
// weight pre-split: 17 matrices of 256x256 -> bf16 hi/lo
// ---------------------------------------------------------------------------
__global__ void wpack_k(const float* __restrict__ relW, const float* __restrict__ entW,
                        const float* __restrict__ headW, const float* __restrict__ tailW,
                        const float* __restrict__ selfW, const float* __restrict__ e2eW,
                        short* __restrict__ wh, short* __restrict__ wl)
{
    int id = blockIdx.x * 256 + threadIdx.x;
    if (id >= 17 * 65536) return;
    int m = id >> 16, e = id & 65535;
    float x;
    if (m == 0)       x = relW[e];
    else if (m == 1)  x = entW[e];
    else if (m < 5)   x = headW[(size_t)(m - 2) * 65536 + e];
    else if (m < 8)   x = tailW[(size_t)(m - 5) * 65536 + e];
    else if (m < 11)  x = selfW[(size_t)(m - 8) * 65536 + e];
    else if (m < 14)  x = e2eW[(size_t)(m - 11) * 196608 + (size_t)(e >> 8) * 768 + (e & 255)];
    else              x = e2eW[(size_t)(m - 14) * 196608 + (size_t)(e >> 8) * 768 + 512 + (e & 255)];
    unsigned short h = f2bf_rne(x);
    wh[id] = (short)h;
    wl[id] = (short)f2bf_rne(x - bf2f(h));
}

// ---------------------------------------------------------------------------
// fp32 64x128 GEMM (only for the tiny Xg GEMM, N=1024)
// ---------------------------------------------------------------------------
template<int GATHER>
__global__ __launch_bounds__(256, 4) void gemm3_k(
    const float* __restrict__ A1, const int* __restrict__ idx,
    const float* __restrict__ W1, int ldw1,
    const float* __restrict__ biasA,
    float* __restrict__ out, int M, int N)
{
    __shared__ float As[16][68];
    __shared__ float Bs[16][132];
    const int tid = threadIdx.x;
    const int row0 = blockIdx.y * 64, col0 = blockIdx.x * 128;
    const int tx = tid & 15, ty = tid >> 4;
    const int srA = tid >> 2, skA = (tid & 3) << 2;
    const int srB = tid >> 1, skB = (tid & 1) << 3;
    const int grA = row0 + srA;
    const bool rvalid = (grA < M);
    const float* aRow1 = nullptr;
    if (rvalid) aRow1 = GATHER ? A1 + (size_t)idx[grA] * 256 : A1 + (size_t)grA * 256;
    const float* wR1 = W1 + (size_t)(col0 + srB) * ldw1;

    float acc[4][8];
    #pragma unroll
    for (int i = 0; i < 4; ++i)
        #pragma unroll
        for (int j = 0; j < 8; ++j) acc[i][j] = 0.f;

    float4 a0, b0, b1;
    auto fetch = [&](int ch) {
        const int k0 = ch << 4;
        if (rvalid) a0 = *(const float4*)(aRow1 + k0 + skA);
        else        a0 = make_float4(0.f, 0.f, 0.f, 0.f);
        b0 = *(const float4*)(wR1 + k0 + skB);
        b1 = *(const float4*)(wR1 + k0 + skB + 4);
    };

    fetch(0);
    for (int ch = 0; ch < 16; ++ch) {
        As[skA + 0][srA] = a0.x; As[skA + 1][srA] = a0.y;
        As[skA + 2][srA] = a0.z; As[skA + 3][srA] = a0.w;
        Bs[skB + 0][srB] = b0.x; Bs[skB + 1][srB] = b0.y;
        Bs[skB + 2][srB] = b0.z; Bs[skB + 3][srB] = b0.w;
        Bs[skB + 4][srB] = b1.x; Bs[skB + 5][srB] = b1.y;
        Bs[skB + 6][srB] = b1.z; Bs[skB + 7][srB] = b1.w;
        __syncthreads();
        if (ch + 1 < 16) fetch(ch + 1);
        #pragma unroll
        for (int kk = 0; kk < 16; ++kk) {
            float av[4], bv[8];
            *(float4*)&av[0] = *(const float4*)&As[kk][ty << 2];
            *(float4*)&bv[0] = *(const float4*)&Bs[kk][tx << 2];
            *(float4*)&bv[4] = *(const float4*)&Bs[kk][(tx << 2) + 64];
            #pragma unroll
            for (int i = 0; i < 4; ++i)
                #pragma unroll
                for (int j = 0; j < 8; ++j) acc[i][j] += av[i] * bv[j];
        }
        __syncthreads();
    }
    #pragma unroll
    for (int i = 0; i < 4; ++i) {
        int r = row0 + (ty << 2) + i;
        if (r >= M) continue;
        float* orow = out + (size_t)r * N;
        #pragma unroll
        for (int jh = 0; jh < 2; ++jh) {
            const int c = col0 + (jh << 6) + (tx << 2);
            float4 v;
            v.x = acc[i][jh * 4 + 0] + biasA[c + 0];
            v.y = acc[i][jh * 4 + 1] + biasA[c + 1];
            v.z = acc[i][jh * 4 + 2] + biasA[c + 2];
            v.w = acc[i][jh * 4 + 3] + biasA[c + 3];
            *(float4*)(orow + c) = v;
        }
    }
}

// ---------------------------------------------------------------------------
// CSR build
// ---------------------------------------------------------------------------
__global__ void csr_count2_k(const int* __restrict__ idxA, int* __restrict__ cntA,
                             const int* __restrict__ idxB, int* __restrict__ cntB)
{
    int k = blockIdx.x * 256 + threadIdx.x;
    if (k >= NNZ_) return;
    if (blockIdx.y == 0) atomicAdd(&cntA[idxA[k] * FF + idxA[NNZ_ + k]], 1);
    else                 atomicAdd(&cntB[idxB[k] * EE + idxB[NNZ_ + k]], 1);
}

__global__ __launch_bounds__(1024) void scan2_k(
    const int* __restrict__ cntA, int* __restrict__ rpA, int* __restrict__ curA, int nA,
    const int* __restrict__ cntB, int* __restrict__ rpB, int* __restrict__ curB, int nB)
{
    const int* cnt = blockIdx.x ? cntB : cntA;
    int* rp  = blockIdx.x ? rpB  : rpA;
    int* cur = blockIdx.x ? curB : curA;
    int n    = blockIdx.x ? nB   : nA;
    __shared__ int sums[1024];
    int t = threadIdx.x;
    int chunk = (n + 1023) / 1024;
    int lo = t * chunk, hi = lo + chunk;
    if (lo > n) lo = n;
    if (hi > n) hi = n;
    int s = 0;
    for (int i = lo; i < hi; ++i) s += cnt[i];
    sums[t] = s;
    __syncthreads();
    for (int off = 1; off < 1024; off <<= 1) {
        int v = (t >= off) ? sums[t - off] : 0;
        __syncthreads();
        sums[t] += v;
        __syncthreads();
    }
    int run = (t == 0) ? 0 : sums[t - 1];
    for (int i = lo; i < hi; ++i) { rp[i] = run; cur[i] = run; run += cnt[i]; }
    if (hi == n) rp[n] = run;
}

__global__ void csr_fill2_k(
    const int* __restrict__ idxA, const float* __restrict__ valA,
    int* __restrict__ curA, int* __restrict__ colA, float* __restrict__ vpA,
    const int* __restrict__ idxB, const float* __restrict__ valB,
    int* __restrict__ curB, int* __restrict__ colB, float* __restrict__ vpB)
{
    int k = blockIdx.x * 256 + threadIdx.x;
    if (k >= NNZ_) return;
    if (blockIdx.y == 0) {
        int row = idxA[k] * FF + idxA[NNZ_ + k];
        int p = atomicAdd(&curA[row], 1);
        colA[p] = idxA[2 * NNZ_ + k];
        vpA[p] = valA[k];
    } else {
        int row = idxB[k] * EE + idxB[NNZ_ + k];
        int p = atomicAdd(&curB[row], 1);
        colB[p] = idxB[2 * NNZ_ + k];
        vpB[p] = valB[k];
    }
}

__global__ void degw_k(const int* __restrict__ rp, const float* __restrict__ vp,
                       float* __restrict__ degw, int n)
{
    int r = blockIdx.x * 256 + threadIdx.x;
    if (r >= n) return;
    float s = 0.f;
    for (int j = rp[r]; j < rp[r + 1]; ++j) s += vp[j];
    degw[r] = s;
}

// ---------------------------------------------------------------------------
// fused e2f gather (relu + norm; e2fnrm written)
// ---------------------------------------------------------------------------
__global__ __launch_bounds__(256) void gather_fused_e2f_k(
    const int* __restrict__ rowptr, const int* __restrict__ col,
    const float* __restrict__ valp, const float* __restrict__ headsrc,
    const float* __restrict__ pr, const float* __restrict__ sm,
    const float* __restrict__ Wtil, float* __restrict__ e2fnrm,
    float* __restrict__ dst, int nrows)
{
    int gid = blockIdx.x * 256 + threadIdx.x;
    int row = gid >> 6, lane = gid & 63;
    if (row >= nrows) return;
    int b = row / FF;
    const float* prb = pr + (size_t)b * EE;
    const float* smb = sm + (size_t)b * EE;
    float4* dp = (float4*)(dst + (size_t)row * DD + (lane << 2));
    float4 acc = *dp;
    float ns = 0.f;
    int j0 = rowptr[row], j1 = rowptr[row + 1];
    for (int j = j0; j < j1; ++j) {
        int c = col[j];
        float v = valp[j];
        float4 x = *(const float4*)(headsrc + ((size_t)b * EE + c) * DD + (lane << 2));
        acc.x += v * x.x; acc.y += v * x.y; acc.z += v * x.z; acc.w += v * x.w;
        ns += v * (prb[c] / fmaxf(smb[c], VSMALL));
    }
    float nrm = Wtil[row] * ns;
    if (lane == 0) e2fnrm[row] = nrm;
    acc.x = fmaxf(acc.x, 0.f) * nrm; acc.y = fmaxf(acc.y, 0.f) * nrm;
    acc.z = fmaxf(acc.z, 0.f) * nrm; acc.w = fmaxf(acc.w, 0.f) * nrm;
    *dp = acc;
}

// dst[row] = sum val*src[b,c]  (pure gather, fp32 out)
__global__ __launch_bounds__(256) void gather_sum_k(
    const int* __restrict__ rowptr, const int* __restrict__ col,
    const float* __restrict__ valp, const float* __restrict__ src,
    float* __restrict__ dst, int nrows, int nrPerB, int ncs)
{
    int gid = blockIdx.x * 256 + threadIdx.x;
    int row = gid >> 6, lane = gid & 63;
    if (row >= nrows) return;
    int b = row / nrPerB;
    float4 acc = make_float4(0.f, 0.f, 0.f, 0.f);
    int j0 = rowptr[row], j1 = rowptr[row + 1];
    for (int j = j0; j < j1; ++j) {
        int c = col[j];
        float v = valp[j];
        float4 x = *(const float4*)(src + ((size_t)b * ncs + c) * DD + (lane << 2));
        acc.x += v * x.x; acc.y += v * x.y; acc.z += v * x.z; acc.w += v * x.w;
    }
    *(float4*)(dst + (size_t)row * DD + (lane << 2)) = acc;
}

// ---------------------------------------------------------------------------
// LSTM v2 (r12 proven): 64 blocks, Whh LDS-cached, 1 grid barrier/step.
// ---------------------------------------------------------------------------
#define LSTM_BLOCKS 64
__global__ __launch_bounds__(256, 1) void lstm2_k(
    const float* __restrict__ Xg, const float* __restrict__ Whh,
    const float* __restrict__ bhh, float* __restrict__ gbuf,
    unsigned* __restrict__ bar, float* __restrict__ qh, float* __restrict__ qne)
{
    __shared__ float wslice[128 * 257];
    __shared__ float hbuf[256];
    __shared__ float cbuf[256];
    __shared__ float gpart[256];
    const int B = blockIdx.x;
    const int b = B >> 3, p = B & 7;
    const int t = threadIdx.x;
    const float* wsrc = Whh + (size_t)p * 128 * 256;
    for (int i = t; i < 128 * 64; i += 256) {
        int row = i >> 6, q4 = (i & 63) << 2;
        float4 w = *(const float4*)(wsrc + (size_t)row * 256 + q4);
        float* d = &wslice[row * 257 + q4];
        d[0] = w.x; d[1] = w.y; d[2] = w.z; d[3] = w.w;
    }
    hbuf[t] = 0.f; cbuf[t] = 0.f;
    __syncthreads();

    unsigned* bar_cnt = bar;
    unsigned* bar_gen = bar + 1;

    for (int step = 0; step < QQ; ++step) {
        {
            const int r = t & 127, half = t >> 7;
            const float* wr = &wslice[r * 257 + half * 128];
            const float* hb = &hbuf[half * 128];
            float acc = 0.f;
            #pragma unroll 8
            for (int k = 0; k < 128; ++k) acc += wr[k] * hb[k];
            gpart[t] = acc;
        }
        __syncthreads();
        if (t < 128) {
            const int gr = p * 128 + t;
            float g = bhh[gr] + Xg[((size_t)b * QQ + step) * 1024 + gr]
                    + gpart[t] + gpart[t + 128];
            gbuf[((size_t)(step & 1) * BB + b) * 1024 + gr] = g;
        }
        __syncthreads();
        if (t == 0) {
            __threadfence();
            const unsigned target = (unsigned)(step + 1) * LSTM_BLOCKS;
            unsigned old = atomicAdd(bar_cnt, 1u);
            if (old == target - 1u) {
                atomicExch(bar_gen, (unsigned)(step + 1));
            } else {
                while (atomicAdd(bar_gen, 0u) < (unsigned)(step + 1)) {}
            }
            __threadfence();
        }
        __syncthreads();
        {
            const float* g = gbuf + ((size_t)(step & 1) * BB + b) * 1024;
            float gi = g[t], gf = g[256 + t], gg = g[512 + t], go = g[768 + t];
            float si = 1.f / (1.f + expf(-gi));
            float sf = 1.f / (1.f + expf(-gf));
            float so = 1.f / (1.f + expf(-go));
            float c = sf * cbuf[t] + si * tanhf(gg);
            float hh = so * tanhf(c);
            cbuf[t] = c;
            hbuf[t] = hh;
            if (p == 0) qh[((size_t)b * QQ + step) * DD + t] = hh;
        }
        __syncthreads();
    }
    if (p == 0) qne[(size_t)b * DD + t] = hbuf[t];
}

// ---------------------------------------------------------------------------
// sim -> softmax -> Wt ; rowmax+Wtil ; e2f_softmax scatter
// ---------------------------------------------------------------------------
__global__ __launch_bounds__(256) void simwt_k(
    const float* __restrict__ qhid, const int* __restrict__ qtext,
    const float* __restrict__ lfe, float* __restrict__ Wt)
{
    __shared__ float qs[QQ * DD];
    __shared__ float qmn[QQ];
    const int b = blockIdx.y;
    const int f = blockIdx.x * 256 + threadIdx.x;
    for (int i = threadIdx.x; i < QQ * DD; i += 256) qs[i] = qhid[(size_t)b * QQ * DD + i];
    if (threadIdx.x < QQ)
        qmn[threadIdx.x] = (qtext[b * QQ + threadIdx.x] != NWORD) ? 0.f : VNEG;
    __syncthreads();
    if (f >= FF) return;
    float acc[QQ];
    #pragma unroll
    for (int q = 0; q < QQ; ++q) acc[q] = 0.f;
    const float* lr = lfe + ((size_t)b * FF + f) * DD;
    for (int d = 0; d < DD; d += 4) {
        float4 x = *(const float4*)(lr + d);
        #pragma unroll
        for (int q = 0; q < QQ; ++q) {
            float4 y = *(const float4*)&qs[q * DD + d];
            acc[q] += x.x * y.x + x.y * y.y + x.z * y.z + x.w * y.w;
        }
    }
    const float inv = 0.0625f;
    float pre[QQ], m = -INFINITY;
    #pragma unroll
    for (int q = 0; q < QQ; ++q) { pre[q] = acc[q] * inv + qmn[q]; m = fmaxf(m, pre[q]); }
    float s = 0.f;
    #pragma unroll
    for (int q = 0; q < QQ; ++q) s += expf(pre[q] - m);
    float wt = 0.f;
    #pragma unroll
    for (int q = 0; q < QQ; ++q) wt += (expf(pre[q] - m) / s) * (acc[q] * inv);
    Wt[(size_t)b * FF + f] = wt;
}

__global__ __launch_bounds__(256) void rowmax_wtil_k(
    const float* __restrict__ Wt, float* __restrict__ Wtil)
{
    __shared__ float red[256];
    int b = blockIdx.x, t = threadIdx.x;
    float m = -INFINITY;
    for (int f = t; f < FF; f += 256) m = fmaxf(m, Wt[b * FF + f]);
    red[t] = m; __syncthreads();
    for (int s = 128; s > 0; s >>= 1) {
        if (t < s) red[t] = fmaxf(red[t], red[t + s]);
        __syncthreads();
    }
    float mx = red[0];
    for (int f = t; f < FF; f += 256) Wtil[b * FF + f] = expf(Wt[b * FF + f] - mx);
}

__global__ void scatter_sm_k(const int* __restrict__ idx, const float* __restrict__ val,
                             const float* __restrict__ Wtil, float* __restrict__ dst)
{
    int k = blockIdx.x * 256 + threadIdx.x;
    if (k >= NNZ_) return;
    int b = idx[k], e = idx[2 * NNZ_ + k], f = idx[NNZ_ + k];
    atomicAdd(&dst[(size_t)b * EE + e], val[k] * Wtil[(size_t)b * FF + f]);
}

// ---------------------------------------------------------------------------
// initial qlin + ebias (float4 weight loads)
// ---------------------------------------------------------------------------
__global__ __launch_bounds__(256) void qlin_ebias_k(
    const float* __restrict__ qne, const float* __restrict__ q2eW,
    const float* __restrict__ q2eb, const float* __restrict__ e2eW,
    const float* __restrict__ e2eb, float* __restrict__ qlin, float* __restrict__ ebias)
{
    __shared__ float xs[DD], qs[DD];
    int b = blockIdx.x, j = threadIdx.x;
    xs[j] = qne[b * DD + j];
    __syncthreads();
    float acc = q2eb[j];
    const float* wr = q2eW + (size_t)j * DD;
    #pragma unroll 4
    for (int k = 0; k < DD; k += 4) {
        float4 w = *(const float4*)(wr + k);
        acc += xs[k] * w.x + xs[k + 1] * w.y + xs[k + 2] * w.z + xs[k + 3] * w.w;
    }
    qlin[b * DD + j] = acc;
    qs[j] = acc;
    __syncthreads();
    float acc2 = e2eb[j];
    const float* wr2 = e2eW + (size_t)j * 768 + 256;
    #pragma unroll 4
    for (int k = 0; k < DD; k += 4) {
        float4 w = *(const float4*)(wr2 + k);
        acc2 += qs[k] * w.x + qs[k + 1] * w.y + qs[k + 2] * w.z + qs[k + 3] * w.w;
    }
    ebias[b * DD + j] = acc2;
}

// ---------------------------------------------------------------------------
// fused pagerank update + vreduce partials
// ---------------------------------------------------------------------------
#define VCH 80
#define NCHK (EE / VCH)   // 25
__global__ __launch_bounds__(256) void vreduce_pr_k(
    const int* __restrict__ f2e_rp, const int* __restrict__ f2e_col,
    const float* __restrict__ f2e_vp, const float* __restrict__ e2fnrm,
    float* __restrict__ pr, const float* __restrict__ lee,
    const float* __restrict__ f2e, float* __restrict__ vpartL,
    float* __restrict__ vpartF, float* __restrict__ vpartS)
{
    int b = blockIdx.y, ch = blockIdx.x, k = threadIdx.x;
    int e0 = ch * VCH;
    __shared__ float prs[VCH];
    if (k < VCH) {
        int row = b * EE + e0 + k;
        float s = 0.f;
        for (int j = f2e_rp[row]; j < f2e_rp[row + 1]; ++j)
            s += f2e_vp[j] * e2fnrm[(size_t)b * FF + f2e_col[j]];
        float v = 0.8f * s + 0.2f * pr[row];
        pr[row] = v;
        prs[k] = v;
    }
    __syncthreads();
    float a1 = 0.f, a2 = 0.f;
    for (int e = 0; e < VCH; ++e) {
        float p = prs[e];
        size_t base = ((size_t)b * EE + e0 + e) * DD + k;
        a1 += p * lee[base];
        a2 += p * f2e[base];
    }
    int pi = ch * BB + b;
    vpartL[(size_t)pi * DD + k] = a1;
    vpartF[(size_t)pi * DD + k] = a2;
    float sp = 0.f;
    for (int e = k; e < VCH; e += 256) sp += prs[e];
    __shared__ float red[256];
    red[k] = sp; __syncthreads();
    for (int s = 128; s > 0; s >>= 1) {
        if (k < s) red[k] += red[k + s];
        __syncthreads();
    }
    if (k == 0) vpartS[pi] = red[0];
}

// ---------------------------------------------------------------------------
// qne update + next layer's qlin/ebias (float4 weight loads)
// ---------------------------------------------------------------------------
__global__ __launch_bounds__(256) void qneupd_qlin_k(
    const float* __restrict__ vpartL, const float* __restrict__ vpartF,
    const float* __restrict__ vpartS, const float* __restrict__ qlinCur,
    const float* __restrict__ W, const float* __restrict__ bias,
    float* __restrict__ qne,
    const float* __restrict__ q2eWn, const float* __restrict__ q2ebn,
    const float* __restrict__ e2eWn, const float* __restrict__ e2ebn,
    float* __restrict__ qlinNext, float* __restrict__ ebiasNext)
{
    __shared__ float s1[DD], s2[DD], s3[DD], qn[DD], qs[DD];
    int b = blockIdx.x, j = threadIdx.x;
    float a1 = 0.f, a3 = 0.f, sp = 0.f;
    for (int ch = 0; ch < NCHK; ++ch) {
        int pi = ch * BB + b;
        a1 += vpartL[(size_t)pi * DD + j];
        a3 += vpartF[(size_t)pi * DD + j];
        sp += vpartS[pi];
    }
    s1[j] = a1; s2[j] = qlinCur[b * DD + j]; s3[j] = a3;
    __syncthreads();
    float acc = sp * bias[j];
    const float* wr = W + (size_t)j * 768;
    #pragma unroll 4
    for (int k = 0; k < DD; k += 4) {
        float4 w0 = *(const float4*)(wr + k);
        float4 w1 = *(const float4*)(wr + 256 + k);
        float4 w2 = *(const float4*)(wr + 512 + k);
        acc += s1[k] * w0.x + s1[k + 1] * w0.y + s1[k + 2] * w0.z + s1[k + 3] * w0.w;
        acc += sp * (s2[k] * w1.x + s2[k + 1] * w1.y + s2[k + 2] * w1.z + s2[k + 3] * w1.w);
        acc += 3.f * (s3[k] * w2.x + s3[k + 1] * w2.y + s3[k + 2] * w2.z + s3[k + 3] * w2.w);
    }
    qne[b * DD + j] = acc;
    qn[j] = acc;
    __syncthreads();
    float aq = q2ebn[j];
    const float* wq = q2eWn + (size_t)j * DD;
    #pragma unroll 4
    for (int k = 0; k < DD; k += 4) {
        float4 w = *(const float4*)(wq + k);
        aq += qn[k] * w.x + qn[k + 1] * w.y + qn[k + 2] * w.z + qn[k + 3] * w.w;
    }
    qlinNext[b * DD + j] = aq;
    qs[j] = aq;
    __syncthreads();
    float ae = e2ebn[j];
    const float* we = e2eWn + (size_t)j * 768 + 256;
    #pragma unroll 4
    for (int k = 0; k < DD; k += 4) {
        float4 w = *(const float4*)(we + k);
        ae += qs[k] * w.x + qs[k + 1] * w.y + qs[k + 2] * w.z + qs[k + 3] * w.w;
    }
    ebiasNext[b * DD + j] = ae;
}

// ---------------------------------------------------------------------------
// epilogue: partial (64 blocks: 8 batches x 8 row-chunks) + combine.
// Semantics: strict > replaces; ties keep smaller index (== np.argmax).
// ---------------------------------------------------------------------------
__global__ __launch_bounds__(256) void final_part_k(
    const float* __restrict__ lee, const float* __restrict__ sw_,
    const float* __restrict__ sb, const int* __restrict__ local_entity,
    const float* __restrict__ ans, float* __restrict__ out,
    float* __restrict__ fpl, float* __restrict__ fpv, int* __restrict__ fpi)
{
    __shared__ float sw[DD];
    int b = blockIdx.x >> 3, ch = blockIdx.x & 7, t = threadIdx.x;
    sw[t] = sw_[t];
    __syncthreads();
    float sb0 = sb[0];
    float lsum = 0.f, bm = -INFINITY;
    int bi = EE;
    int e0 = ch * 250;
    for (int e = e0 + t; e < e0 + 250; e += 256) {
        const float* a = lee + ((size_t)b * EE + e) * DD;
        float s = sb0;
        for (int k = 0; k < DD; k += 4) {
            float4 v = *(const float4*)(a + k);
            s += v.x * sw[k] + v.y * sw[k + 1] + v.z * sw[k + 2] + v.w * sw[k + 3];
        }
        float mask = (local_entity[b * EE + e] != NENT) ? 1.f : 0.f;
        float smv = s + (1.f - mask) * VNEG;
        float sig;
        if (smv >= 0.f) sig = 1.f / (1.f + expf(-smv));
        else { float es = expf(smv); sig = es / (1.f + es); }
        out[1 + BB + b * EE + e] = sig * mask;
        lsum += fmaxf(s, 0.f) - s * ans[b * EE + e] + log1pf(expf(-fabsf(s)));
        if (smv > bm) { bm = smv; bi = e; }
    }
    __shared__ float rv[256]; __shared__ int ri[256]; __shared__ float rl[256];
    rv[t] = bm; ri[t] = bi; rl[t] = lsum;
    __syncthreads();
    for (int s = 128; s > 0; s >>= 1) {
        if (t < s) {
            rl[t] += rl[t + s];
            if (rv[t + s] > rv[t] || (rv[t + s] == rv[t] && ri[t + s] < ri[t])) {
                rv[t] = rv[t + s]; ri[t] = ri[t + s];
            }
        }
        __syncthreads();
    }
    if (t == 0) { fpl[blockIdx.x] = rl[0]; fpv[blockIdx.x] = rv[0]; fpi[blockIdx.x] = ri[0]; }
}

__global__ void final_combine_k(const float* __restrict__ fpl,
                                const float* __restrict__ fpv,
                                const int* __restrict__ fpi, float* __restrict__ out)
{
    __shared__ float lsums[BB];
    int t = threadIdx.x;
    if (t < BB) {
        float ls = 0.f, bm = -INFINITY;
        int bi = EE;
        for (int ch = 0; ch < 8; ++ch) {
            int i = t * 8 + ch;
            ls += fpl[i];
            if (fpv[i] > bm || (fpv[i] == bm && fpi[i] < bi)) { bm = fpv[i]; bi = fpi[i]; }
        }
        out[1 + t] = (float)bi;
        lsums[t] = ls;
    }
    __syncthreads();
    if (t == 0) {
        float s = 0.f;
        for (int b = 0; b < BB; ++b) s += lsums[b];
        out[0] = s / (float)(BB * EE);
    }
}

// ---------------------------------------------------------------------------
extern "C" void kernel_launch(void* const* d_in, const int* in_sizes, int n_in,
                              void* d_out, int out_size, void* d_ws, size_t ws_size,
                              hipStream_t stream)
{
    (void)in_sizes; (void)n_in; (void)out_size; (void)ws_size;
    const int*   local_entity = (const int*)d_in[0];
    const float* q2e_adj      = (const float*)d_in[1];
    const int*   kb_fact_rel  = (const int*)d_in[2];
    const int*   query_text   = (const int*)d_in[3];
    const float* answer_dist  = (const float*)d_in[4];
    const int*   e2f_idx      = (const int*)d_in[5];
    const float* e2f_val      = (const float*)d_in[6];
    const int*   f2e_idx      = (const int*)d_in[7];
    const float* f2e_val      = (const float*)d_in[8];
    const float* entity_table = (const float*)d_in[9];
    const float* ent_W        = (const float*)d_in[10];
    const float* ent_b        = (const float*)d_in[11];
    const float* rel_table    = (const float*)d_in[12];
    const float* rel_W        = (const float*)d_in[13];
    const float* rel_b        = (const float*)d_in[14];
    const float* word_table   = (const float*)d_in[15];
    const float* Wih          = (const float*)d_in[16];
    const float* Whh          = (const float*)d_in[17];
    const float* bih          = (const float*)d_in[18];
    const float* bhh          = (const float*)d_in[19];
    const float* q2e_W        = (const float*)d_in[20];
    const float* q2e_b        = (const float*)d_in[21];
    const float* e2q_W        = (const float*)d_in[22];
    const float* e2q_b        = (const float*)d_in[23];
    const float* e2e_W        = (const float*)d_in[24];
    const float* e2e_b        = (const float*)d_in[25];
    const float* head_W       = (const float*)d_in[26];
    const float* head_b       = (const float*)d_in[27];
    const float* tail_W       = (const float*)d_in[28];
    const float* tail_b       = (const float*)d_in[29];
    const float* self_W       = (const float*)d_in[30];
    const float* self_b       = (const float*)d_in[31];
    const float* score_W      = (const float*)d_in[32];
    const float* score_b      = (const float*)d_in[33];

    const int NR1 = BB * FF;   // 48000
    const int NR2 = BB * EE;   // 16000

    float* ws = (float*)d_ws;
    size_t off = 0;
    auto alloc = [&](size_t n) { float* p = ws + off; off += n; return p; };
    auto salloc = [&](size_t nshorts) { short* p = (short*)(ws + off); off += (nshorts + 1) / 2; return p; };
    float* Xg      = alloc((size_t)BB * QQ * 1024);
    float* gbuf    = alloc((size_t)2 * BB * 1024);
    float* qh      = alloc((size_t)BB * QQ * DD);
    float* qne     = alloc(BB * DD);
    float* lfe     = alloc((size_t)NR1 * DD);
    float* leeA    = alloc((size_t)NR2 * DD);
    float* leeB    = alloc((size_t)NR2 * DD);
    float* Wt      = alloc(BB * FF);
    float* Wtil    = alloc(BB * FF);
    float* e2fsm   = alloc(BB * EE);
    float* pr      = alloc(BB * EE);
    float* qlinA   = alloc(BB * DD);
    float* qlinB   = alloc(BB * DD);
    float* ebiasA  = alloc(BB * DD);
    float* ebiasB  = alloc(BB * DD);
    float* e2fnrm  = alloc(BB * FF);
    float* fpl     = alloc(64);
    float* fpv     = alloc(64);
    float* bufC    = alloc((size_t)NR2 * DD);
    float* e2fT    = alloc((size_t)NR1 * DD);
    float* f2eT    = alloc((size_t)NR2 * DD);
    float* tmp     = alloc((size_t)NR2 * DD);
    float* vpartL  = alloc((size_t)NCHK * BB * DD);
    float* vpartF  = alloc((size_t)NCHK * BB * DD);
    float* vpartS  = alloc(NCHK * BB);
    float* degw2   = alloc(NR2);
    float* e2f_vp  = alloc(NNZ_);
    float* f2e_vp  = alloc(NNZ_);
    short* wbh     = salloc((size_t)17 * 65536);
    short* wbl     = salloc((size_t)17 * 65536);
    int* ib = (int*)(ws + off);
    size_t ioff = 0;
    auto ialloc = [&](size_t n) { int* p = ib + ioff; ioff += n; return p; };
    int* e2f_cnt = ialloc(NR1);
    int* e2f_rp  = ialloc(NR1 + 1);
    int* e2f_cur = ialloc(NR1);
    int* e2f_col = ialloc(NNZ_);
    int* f2e_cnt = ialloc(NR2);
    int* f2e_rp  = ialloc(NR2 + 1);
    int* f2e_cur = ialloc(NR2);
    int* f2e_col = ialloc(NNZ_);
    int* fpi     = ialloc(64);
    unsigned* bar = (unsigned*)ialloc(2);

    auto WH = [&](int m) { return wbh + (size_t)m * 65536; };
    auto WL = [&](int m) { return wbl + (size_t)m * 65536; };

    float* outp = (float*)d_out;
    const int SCB = (NNZ_ + 255) / 256;

    // ---- weight pre-split ----
    wpack_k<<<(17 * 65536) / 256, 256, 0, stream>>>(rel_W, ent_W, head_W, tail_W,
                                                    self_W, e2e_W, wbh, wbl);

    // ---- CSR builds ----
    hipMemsetAsync(e2f_cnt, 0, NR1 * sizeof(int), stream);
    hipMemsetAsync(f2e_cnt, 0, NR2 * sizeof(int), stream);
    csr_count2_k<<<dim3(SCB, 2), 256, 0, stream>>>(e2f_idx, e2f_cnt, f2e_idx, f2e_cnt);
    scan2_k<<<2, 1024, 0, stream>>>(e2f_cnt, e2f_rp, e2f_cur, NR1,
                                    f2e_cnt, f2e_rp, f2e_cur, NR2);
    csr_fill2_k<<<dim3(SCB, 2), 256, 0, stream>>>(
        e2f_idx, e2f_val, e2f_cur, e2f_col, e2f_vp,
        f2e_idx, f2e_val, f2e_cur, f2e_col, f2e_vp);
    degw_k<<<(NR2 + 255) / 256, 256, 0, stream>>>(f2e_rp, f2e_vp, degw2, NR2);

    // ---- LSTM (Xg GEMM + 64-block LDS-cached recurrence) ----
    gemm3_k<1><<<dim3(8, 3), 256, 0, stream>>>(
        word_table, query_text, Wih, 256, bih, Xg, BB * QQ, 1024);
    hipMemsetAsync(bar, 0, 2 * sizeof(unsigned), stream);
    lstm2_k<<<LSTM_BLOCKS, 256, 0, stream>>>(Xg, Whh, bhh, gbuf, bar, qh, qne);

    // ---- embeddings: rel + ent gathered GEMMs, ONE MFMA dispatch ----
    mgemm_pair_k<1><<<dim3(2, 375 + 125), 256, 0, stream>>>(
        rel_table, kb_fact_rel, WH(0), WL(0), rel_b, lfe, 375,
        entity_table, local_entity, WH(1), WL(1), ent_b, leeA);

    // ---- attention -> W_tilde ----
    simwt_k<<<dim3((FF + 255) / 256, BB), 256, 0, stream>>>(qh, query_text, lfe, Wt);
    rowmax_wtil_k<<<BB, 256, 0, stream>>>(Wt, Wtil);

    // ---- e2f_softmax ----
    hipMemsetAsync(e2fsm, 0, BB * EE * sizeof(float), stream);
    scatter_sm_k<<<SCB, 256, 0, stream>>>(e2f_idx, e2f_val, Wtil, e2fsm);

    // ---- pagerank init + initial qlin/ebias ----
    hipMemcpyAsync(pr, q2e_adj, BB * EE * sizeof(float), hipMemcpyDeviceToDevice, stream);
    qlin_ebias_k<<<BB, 256, 0, stream>>>(qne, q2e_W, q2e_b, e2e_W, e2e_b, qlinA, ebiasA);

    float* lee = leeA;   float* lee2 = leeB;
    float* qlinCur = qlinA;  float* qlinNxt = qlinB;
    float* ebiasCur = ebiasA; float* ebiasNxt = ebiasB;

    for (int i = 0; i < 3; ++i) {
        const float* headbi = head_b + i * DD;
        const float* tailbi = tail_b + i * DD;
        const float* selfbi = self_b + i * DD;

        // head(lee) -> bufC  AND  self(lfe) -> e2fT, one MFMA dispatch
        mgemm_pair_k<0><<<dim3(2, 125 + 375), 256, 0, stream>>>(
            lee, nullptr, WH(2 + i), WL(2 + i), headbi, bufC, 125,
            lfe, nullptr, WH(8 + i), WL(8 + i), selfbi, e2fT);

        // e2fT = relu(e2fT + gather_e2f(bufC)) * nrm ; e2fnrm written
        gather_fused_e2f_k<<<(NR1 * 64) / 256, 256, 0, stream>>>(
            e2f_rp, e2f_col, e2f_vp, bufC, pr, e2fsm, Wtil, e2fnrm, e2fT, NR1);

        // tmp = gather_f2e(e2fT)
        gather_sum_k<<<(NR2 * 64) / 256, 256, 0, stream>>>(
            f2e_rp, f2e_col, f2e_vp, e2fT, tmp, NR2, EE, FF);

        // f2eT = relu(lee@selfW^T + tmp@tailW^T + selfb + degw*tailb)
        mgemm_k<0, 1, 1, 1, 0><<<dim3(2, 125), 256, 0, stream>>>(
            lee, nullptr, tmp, 1.f, WH(8 + i), WL(8 + i), WH(5 + i), WL(5 + i),
            selfbi, degw2, tailbi, f2eT);

        // pagerank update + vreduce + qneupd: DEAD for last layer (qne/pr unused)
        if (i < 2) {
            vreduce_pr_k<<<dim3(NCHK, BB), 256, 0, stream>>>(
                f2e_rp, f2e_col, f2e_vp, e2fnrm, pr, lee, f2eT, vpartL, vpartF, vpartS);
            const float* e2qWi = e2q_W + (size_t)i * DD * 3 * DD;
            const float* e2qbi = e2q_b + i * DD;
            const float* q2eWn = q2e_W + (size_t)(i + 1) * DD * DD;
            const float* q2ebn = q2e_b + (i + 1) * DD;
            const float* e2eWn = e2e_W + (size_t)(i + 1) * DD * 3 * DD;
            const float* e2ebn = e2e_b + (i + 1) * DD;
            qneupd_qlin_k<<<BB, 256, 0, stream>>>(
                vpartL, vpartF, vpartS, qlinCur, e2qWi, e2qbi, qne,
                q2eWn, q2ebn, e2eWn, e2ebn, qlinNxt, ebiasNxt);
        }

        // lee2 = relu(lee@e2eA^T + 3*f2eT@e2eB^T + ebias[b])  (uses layer-i ebias)
        mgemm_k<0, 1, 1, 0, 1><<<dim3(2, 125), 256, 0, stream>>>(
            lee, nullptr, f2eT, 3.f, WH(11 + i), WL(11 + i), WH(14 + i), WL(14 + i),
            ebiasCur, nullptr, nullptr, lee2);

        // buffer rotation AFTER the last consumer of ebiasCur/lee
        { float* t = lee; lee = lee2; lee2 = t; }
        if (i < 2) {
            { float* t = qlinCur; qlinCur = qlinNxt; qlinNxt = t; }
            { float* t = ebiasCur; ebiasCur = ebiasNxt; ebiasNxt = t; }
        }
    }

    // ---- epilogue: 64-block partials + combine ----
    final_part_k<<<64, 256, 0, stream>>>(lee, score_W, score_b, local_entity,
                                         answer_dist, outp, fpl, fpv, fpi);
    final_combine_k<<<1, 64, 0, stream>>>(fpl, fpv, fpi, outp);
}

// Round 15
// 1102.760 us; speedup vs baseline: 1.2135x; 1.0193x over previous
//
#include <hip/hip_runtime.h>
#include <math.h>

#define BB 8
#define EE 2000
#define FF 6000
#define QQ 20
#define DD 256
#define NENT 400000
#define NWORD 60000
#define NNZ_ 96000
#define VNEG  (-1e11f)
#define VSMALL 1e-10f

typedef __attribute__((ext_vector_type(8))) short short8v;
typedef __attribute__((ext_vector_type(4))) short short4v;
typedef __attribute__((ext_vector_type(4))) float f32x4;

__device__ __forceinline__ unsigned short f2bf_rne(float x)
{
    unsigned u = __float_as_uint(x);
    u += 0x7FFFu + ((u >> 16) & 1u);
    return (unsigned short)(u >> 16);
}
__device__ __forceinline__ float bf2f(unsigned short h)
{
    return __uint_as_float((unsigned)h << 16);
}

// ---------------------------------------------------------------------------
// MFMA split-bf16 GEMM (r10 proven): out = act(A@W^T + bias).
// A fp32 in global; staged per 64-K chunk as hi/lo bf16 into frag-major LDS.
// Block 128x128, 4 waves 2x2 (wave 64x64). __launch_bounds__(256,2).
// ---------------------------------------------------------------------------
template<int GATHER, int DUALW, int RELU, int RS, int BIASB>
__device__ __forceinline__ void mgemm_body(
    const float* __restrict__ A1, const int* __restrict__ idx,
    const float* __restrict__ A2, float sA2,
    const short* __restrict__ W1h, const short* __restrict__ W1l,
    const short* __restrict__ W2h, const short* __restrict__ W2l,
    const float* __restrict__ biasA,
    const float* __restrict__ rowscale, const float* __restrict__ bias2,
    float* __restrict__ out, int by, int bx,
    short* __restrict__ Ah, short* __restrict__ Al)
{
    const int tid = threadIdx.x;
    const int lane = tid & 63, wv = tid >> 6;
    const int wrow = wv >> 1, wcol = wv & 1;
    const int row0 = by * 128, col0 = bx * 128;

    const int sr = tid >> 1;
    const int sko = (tid & 1) << 5;
    const int grow = row0 + sr;
    const float* aRow1 = GATHER ? A1 + (size_t)idx[grow] * 256 : A1 + (size_t)grow * 256;
    const float* aRow2 = DUALW ? A2 + (size_t)grow * 256 : nullptr;

    f32x4 acc[4][4];
    #pragma unroll
    for (int i = 0; i < 4; ++i)
        #pragma unroll
        for (int j = 0; j < 4; ++j) acc[i][j] = (f32x4){0.f, 0.f, 0.f, 0.f};

    const int nch = DUALW ? 8 : 4;
    for (int ch = 0; ch < nch; ++ch) {
        const bool hi2 = DUALW && (ch >= 4);
        const float* ar = hi2 ? aRow2 : aRow1;
        const int kbase = (ch & 3) << 6;
        #pragma unroll
        for (int q = 0; q < 8; ++q) {
            const int kc = sko + (q << 2);
            float4 a = *(const float4*)(ar + kbase + kc);
            if (DUALW && hi2) { a.x *= sA2; a.y *= sA2; a.z *= sA2; a.w *= sA2; }
            unsigned short h0 = f2bf_rne(a.x), h1 = f2bf_rne(a.y),
                           h2 = f2bf_rne(a.z), h3 = f2bf_rne(a.w);
            unsigned short l0 = f2bf_rne(a.x - bf2f(h0)), l1 = f2bf_rne(a.y - bf2f(h1)),
                           l2 = f2bf_rne(a.z - bf2f(h2)), l3 = f2bf_rne(a.w - bf2f(h3));
            const int tI = ((sr >> 4) << 1) + (kc >> 5);
            const int off = (tI << 9) + ((((sr & 15)) + (((kc >> 3) & 3) << 4)) << 3) + (kc & 7);
            *(short4v*)(Ah + off) = (short4v){(short)h0, (short)h1, (short)h2, (short)h3};
            *(short4v*)(Al + off) = (short4v){(short)l0, (short)l1, (short)l2, (short)l3};
        }
        __syncthreads();
        const short* Wh = hi2 ? W2h : W1h;
        const short* Wl = hi2 ? W2l : W1l;
        #pragma unroll
        for (int ks = 0; ks < 2; ++ks) {
            const int kg = kbase + (ks << 5) + ((lane >> 4) << 3);
            short8v bh[4], bl[4];
            #pragma unroll
            for (int ct = 0; ct < 4; ++ct) {
                const int c = col0 + (wcol << 6) + (ct << 4) + (lane & 15);
                bh[ct] = *(const short8v*)(Wh + (size_t)c * 256 + kg);
                bl[ct] = *(const short8v*)(Wl + (size_t)c * 256 + kg);
            }
            #pragma unroll
            for (int rt = 0; rt < 4; ++rt) {
                const int tI = (((wrow << 2) + rt) << 1) + ks;
                const short8v avh = *(const short8v*)(Ah + (tI << 9) + (lane << 3));
                const short8v avl = *(const short8v*)(Al + (tI << 9) + (lane << 3));
                #pragma unroll
                for (int ct = 0; ct < 4; ++ct) {
                    acc[rt][ct] = __builtin_amdgcn_mfma_f32_16x16x32_bf16(avh, bh[ct], acc[rt][ct], 0, 0, 0);
                    acc[rt][ct] = __builtin_amdgcn_mfma_f32_16x16x32_bf16(avh, bl[ct], acc[rt][ct], 0, 0, 0);
                    acc[rt][ct] = __builtin_amdgcn_mfma_f32_16x16x32_bf16(avl, bh[ct], acc[rt][ct], 0, 0, 0);
                }
            }
        }
        __syncthreads();
    }
    #pragma unroll
    for (int rt = 0; rt < 4; ++rt) {
        const int rb = row0 + (wrow << 6) + (rt << 4) + ((lane >> 4) << 2);
        #pragma unroll
        for (int ct = 0; ct < 4; ++ct) {
            const int c = col0 + (wcol << 6) + (ct << 4) + (lane & 15);
            #pragma unroll
            for (int j = 0; j < 4; ++j) {
                const int r = rb + j;
                float v = acc[rt][ct][j];
                v += BIASB ? biasA[(size_t)(r / EE) * 256 + c] : biasA[c];
                if (RS) v += rowscale[r] * bias2[c];
                if (RELU) v = fmaxf(v, 0.f);
                out[(size_t)r * 256 + c] = v;
            }
        }
    }
}

template<int GATHER, int DUALW, int RELU, int RS, int BIASB>
__global__ __launch_bounds__(256, 2) void mgemm_k(
    const float* __restrict__ A1, const int* __restrict__ idx,
    const float* __restrict__ A2, float sA2,
    const short* __restrict__ W1h, const short* __restrict__ W1l,
    const short* __restrict__ W2h, const short* __restrict__ W2l,
    const float* __restrict__ biasA,
    const float* __restrict__ rowscale, const float* __restrict__ bias2,
    float* __restrict__ out)
{
    __shared__ short Ah[16 * 512];
    __shared__ short Al[16 * 512];
    mgemm_body<GATHER, DUALW, RELU, RS, BIASB>(A1, idx, A2, sA2, W1h, W1l, W2h, W2l,
        biasA, rowscale, bias2, out, blockIdx.y, blockIdx.x, Ah, Al);
}

template<int GATHER>
__global__ __launch_bounds__(256, 2) void mgemm_pair_k(
    const float* __restrict__ Aa, const int* __restrict__ idxA,
    const short* __restrict__ Wah, const short* __restrict__ Wal,
    const float* __restrict__ ba, float* __restrict__ outa, int nya,
    const float* __restrict__ Ab, const int* __restrict__ idxB,
    const short* __restrict__ Wbh, const short* __restrict__ Wbl,
    const float* __restrict__ bb, float* __restrict__ outb)
{
    __shared__ short Ah[16 * 512];
    __shared__ short Al[16 * 512];
    const int by = blockIdx.y;
    if (by < nya)
        mgemm_body<GATHER, 0, 0, 0, 0>(Aa, idxA, nullptr, 1.f, Wah, Wal, nullptr, nullptr,
            ba, nullptr, nullptr, outa, by, blockIdx.x, Ah, Al);
    else
        mgemm_body<GATHER, 0, 0, 0, 0>(Ab, idxB, nullptr, 1.f, Wbh, Wbl, nullptr, nullptr,
            bb, nullptr, nullptr, outb, by - nya, blockIdx.x, Ah, Al);
}

// ---------------------------------------------------------------------------
// vreduce body (for tail_k): pagerank update + vreduce partials
// ---------------------------------------------------------------------------
#define VCH 80
#define NCHK (EE / VCH)   // 25
__device__ __forceinline__ void vreduce_body(
    int ch, int b, int k,
    const int* __restrict__ f2e_rp, const int* __restrict__ f2e_col,
    const float* __restrict__ f2e_vp, const float* __restrict__ e2fnrm,
    float* __restrict__ pr, const float* __restrict__ lee,
    const float* __restrict__ f2e, float* __restrict__ vpartL,
    float* __restrict__ vpartF, float* __restrict__ vpartS,
    float* __restrict__ lds)
{
    float* prs = lds;           // VCH floats
    float* red = lds + 128;     // 256 floats
    int e0 = ch * VCH;
    if (k < VCH) {
        int row = b * EE + e0 + k;
        float s = 0.f;
        for (int j = f2e_rp[row]; j < f2e_rp[row + 1]; ++j)
            s += f2e_vp[j] * e2fnrm[(size_t)b * FF + f2e_col[j]];
        float v = 0.8f * s + 0.2f * pr[row];
        pr[row] = v;
        prs[k] = v;
    }
    __syncthreads();
    float a1 = 0.f, a2 = 0.f;
    for (int e = 0; e < VCH; ++e) {
        float p = prs[e];
        size_t base = ((size_t)b * EE + e0 + e) * DD + k;
        a1 += p * lee[base];
        a2 += p * f2e[base];
    }
    int pi = ch * BB + b;
    vpartL[(size_t)pi * DD + k] = a1;
    vpartF[(size_t)pi * DD + k] = a2;
    float sp = 0.f;
    for (int e = k; e < VCH; e += 256) sp += prs[e];
    red[k] = sp; __syncthreads();
    for (int s = 128; s > 0; s >>= 1) {
        if (k < s) red[k] += red[k + s];
        __syncthreads();
    }
    if (k == 0) vpartS[pi] = red[0];
}

// ---------------------------------------------------------------------------
// tail_k: lee2 GEMM (blocks 0..249) + vreduce_pr (250..449, when DOV)
// Independent: GEMM reads lee/f2eT/ebias -> lee2; vreduce reads lee/f2eT/e2fnrm
// -> pr/vpart. r11-verified merge structure.
// ---------------------------------------------------------------------------
template<int DOV>
__global__ __launch_bounds__(256, 2) void tail_k(
    const float* __restrict__ lee, const float* __restrict__ f2eT,
    const short* __restrict__ WaH, const short* __restrict__ WaL,
    const short* __restrict__ WbH, const short* __restrict__ WbL,
    const float* __restrict__ ebias, float* __restrict__ lee2,
    const int* __restrict__ f2e_rp, const int* __restrict__ f2e_col,
    const float* __restrict__ f2e_vp, const float* __restrict__ e2fnrm,
    float* __restrict__ pr, float* __restrict__ vpartL,
    float* __restrict__ vpartF, float* __restrict__ vpartS)
{
    __shared__ char ldsbuf[32768];
    int blk = blockIdx.x;
    if (blk < 250) {
        short* Ah = (short*)ldsbuf; short* Al = Ah + 8192;
        mgemm_body<0, 1, 1, 0, 1>(lee, nullptr, f2eT, 3.f, WaH, WaL, WbH, WbL,
            ebias, nullptr, nullptr, lee2, blk >> 1, blk & 1, Ah, Al);
    } else if (DOV) {
        int v = blk - 250;
        vreduce_body(v >> 3, v & 7, threadIdx.x, f2e_rp, f2e_col, f2e_vp, e2fnrm,
                     pr, lee, f2eT, vpartL, vpartF, vpartS, (float*)ldsbuf);
    }
}

// ---------------------------------------------------------------------------
// fp32 64x128 GEMM body (Xg GEMM, N=1024, gathered)
// ---------------------------------------------------------------------------
__device__ __forceinline__ void gemm3_body(
    const float* __restrict__ A1, const int* __restrict__ idx,
    const float* __restrict__ W1, int ldw1,
    const float* __restrict__ biasA,
    float* __restrict__ out, int M, int N, int by, int bx,
    float (*As)[68], float (*Bs)[132])
{
    const int tid = threadIdx.x;
    const int row0 = by * 64, col0 = bx * 128;
    const int tx = tid & 15, ty = tid >> 4;
    const int srA = tid >> 2, skA = (tid & 3) << 2;
    const int srB = tid >> 1, skB = (tid & 1) << 3;
    const int grA = row0 + srA;
    const bool rvalid = (grA < M);
    const float* aRow1 = nullptr;
    if (rvalid) aRow1 = A1 + (size_t)idx[grA] * 256;
    const float* wR1 = W1 + (size_t)(col0 + srB) * ldw1;

    float acc[4][8];
    #pragma unroll
    for (int i = 0; i < 4; ++i)
        #pragma unroll
        for (int j = 0; j < 8; ++j) acc[i][j] = 0.f;

    float4 a0, b0, b1;
    auto fetch = [&](int ch) {
        const int k0 = ch << 4;
        if (rvalid) a0 = *(const float4*)(aRow1 + k0 + skA);
        else        a0 = make_float4(0.f, 0.f, 0.f, 0.f);
        b0 = *(const float4*)(wR1 + k0 + skB);
        b1 = *(const float4*)(wR1 + k0 + skB + 4);
    };

    fetch(0);
    for (int ch = 0; ch < 16; ++ch) {
        As[skA + 0][srA] = a0.x; As[skA + 1][srA] = a0.y;
        As[skA + 2][srA] = a0.z; As[skA + 3][srA] = a0.w;
        Bs[skB + 0][srB] = b0.x; Bs[skB + 1][srB] = b0.y;
        Bs[skB + 2][srB] = b0.z; Bs[skB + 3][srB] = b0.w;
        Bs[skB + 4][srB] = b1.x; Bs[skB + 5][srB] = b1.y;
        Bs[skB + 6][srB] = b1.z; Bs[skB + 7][srB] = b1.w;
        __syncthreads();
        if (ch + 1 < 16) fetch(ch + 1);
        #pragma unroll
        for (int kk = 0; kk < 16; ++kk) {
            float av[4], bv[8];
            *(float4*)&av[0] = *(const float4*)&As[kk][ty << 2];
            *(float4*)&bv[0] = *(const float4*)&Bs[kk][tx << 2];
            *(float4*)&bv[4] = *(const float4*)&Bs[kk][(tx << 2) + 64];
            #pragma unroll
            for (int i = 0; i < 4; ++i)
                #pragma unroll
                for (int j = 0; j < 8; ++j) acc[i][j] += av[i] * bv[j];
        }
        __syncthreads();
    }
    #pragma unroll
    for (int i = 0; i < 4; ++i) {
        int r = row0 + (ty << 2) + i;
        if (r >= M) continue;
        float* orow = out + (size_t)r * N;
        #pragma unroll
        for (int jh = 0; jh < 2; ++jh) {
            const int c = col0 + (jh << 6) + (tx << 2);
            float4 v;
            v.x = acc[i][jh * 4 + 0] + biasA[c + 0];
            v.y = acc[i][jh * 4 + 1] + biasA[c + 1];
            v.z = acc[i][jh * 4 + 2] + biasA[c + 2];
            v.w = acc[i][jh * 4 + 3] + biasA[c + 3];
            *(float4*)(orow + c) = v;
        }
    }
}

// ---------------------------------------------------------------------------
// prologue_k: wpack (blk 0..4351) + CSR counts (4352..5101) + Xg GEMM
// (5102..5125), all mutually independent, ONE dispatch.
// ---------------------------------------------------------------------------
__global__ __launch_bounds__(256, 4) void prologue_k(
    const float* __restrict__ relW, const float* __restrict__ entW,
    const float* __restrict__ headW, const float* __restrict__ tailW,
    const float* __restrict__ selfW, const float* __restrict__ e2eW,
    short* __restrict__ wh, short* __restrict__ wl,
    const int* __restrict__ e2f_idx, int* __restrict__ e2f_cnt,
    const int* __restrict__ f2e_idx, int* __restrict__ f2e_cnt,
    const float* __restrict__ word_table, const int* __restrict__ query_text,
    const float* __restrict__ Wih, const float* __restrict__ bih,
    float* __restrict__ Xg)
{
    __shared__ char lds[12800];
    int blk = blockIdx.x;
    if (blk < 4352) {
        int id = blk * 256 + threadIdx.x;   // exactly covers 17*65536
        int m = id >> 16, e = id & 65535;
        float x;
        if (m == 0)       x = relW[e];
        else if (m == 1)  x = entW[e];
        else if (m < 5)   x = headW[(size_t)(m - 2) * 65536 + e];
        else if (m < 8)   x = tailW[(size_t)(m - 5) * 65536 + e];
        else if (m < 11)  x = selfW[(size_t)(m - 8) * 65536 + e];
        else if (m < 14)  x = e2eW[(size_t)(m - 11) * 196608 + (size_t)(e >> 8) * 768 + (e & 255)];
        else              x = e2eW[(size_t)(m - 14) * 196608 + (size_t)(e >> 8) * 768 + 512 + (e & 255)];
        unsigned short h = f2bf_rne(x);
        wh[id] = (short)h;
        wl[id] = (short)f2bf_rne(x - bf2f(h));
    } else if (blk < 5102) {
        int c = blk - 4352;                 // 0..749; 375 blocks per edge set
        int k = (c % 375) * 256 + threadIdx.x;   // exactly covers NNZ_
        if (c < 375) atomicAdd(&e2f_cnt[e2f_idx[k] * FF + e2f_idx[NNZ_ + k]], 1);
        else         atomicAdd(&f2e_cnt[f2e_idx[k] * EE + f2e_idx[NNZ_ + k]], 1);
    } else {
        int g = blk - 5102;                 // 0..23 -> bx 0..7, by 0..2
        float (*As)[68]  = (float(*)[68])lds;
        float (*Bs)[132] = (float(*)[132])(lds + 4352);
        gemm3_body(word_table, query_text, Wih, 256, bih, Xg,
                   BB * QQ, 1024, g / 8, g % 8, As, Bs);
    }
}

// ---------------------------------------------------------------------------
// CSR scan + fill + degw
// ---------------------------------------------------------------------------
__global__ __launch_bounds__(1024) void scan2_k(
    const int* __restrict__ cntA, int* __restrict__ rpA, int* __restrict__ curA, int nA,
    const int* __restrict__ cntB, int* __restrict__ rpB, int* __restrict__ curB, int nB)
{
    const int* cnt = blockIdx.x ? cntB : cntA;
    int* rp  = blockIdx.x ? rpB  : rpA;
    int* cur = blockIdx.x ? curB : curA;
    int n    = blockIdx.x ? nB   : nA;
    __shared__ int sums[1024];
    int t = threadIdx.x;
    int chunk = (n + 1023) / 1024;
    int lo = t * chunk, hi = lo + chunk;
    if (lo > n) lo = n;
    if (hi > n) hi = n;
    int s = 0;
    for (int i = lo; i < hi; ++i) s += cnt[i];
    sums[t] = s;
    __syncthreads();
    for (int off = 1; off < 1024; off <<= 1) {
        int v = (t >= off) ? sums[t - off] : 0;
        __syncthreads();
        sums[t] += v;
        __syncthreads();
    }
    int run = (t == 0) ? 0 : sums[t - 1];
    for (int i = lo; i < hi; ++i) { rp[i] = run; cur[i] = run; run += cnt[i]; }
    if (hi == n) rp[n] = run;
}

__global__ void csr_fill2_k(
    const int* __restrict__ idxA, const float* __restrict__ valA,
    int* __restrict__ curA, int* __restrict__ colA, float* __restrict__ vpA,
    const int* __restrict__ idxB, const float* __restrict__ valB,
    int* __restrict__ curB, int* __restrict__ colB, float* __restrict__ vpB)
{
    int k = blockIdx.x * 256 + threadIdx.x;
    if (k >= NNZ_) return;
    if (blockIdx.y == 0) {
        int row = idxA[k] * FF + idxA[NNZ_ + k];
        int p = atomicAdd(&curA[row], 1);
        colA[p] = idxA[2 * NNZ_ + k];
        vpA[p] = valA[k];
    } else {
        int row = idxB[k] * EE + idxB[NNZ_ + k];
        int p = atomicAdd(&curB[row], 1);
        colB[p] = idxB[2 * NNZ_ + k];
        vpB[p] = valB[k];
    }
}

__global__ void degw_k(const int* __restrict__ rp, const float* __restrict__ vp,
                       float* __restrict__ degw, int n)
{
    int r = blockIdx.x * 256 + threadIdx.x;
    if (r >= n) return;
    float s = 0.f;
    for (int j = rp[r]; j < rp[r + 1]; ++j) s += vp[j];
    degw[r] = s;
}

// ---------------------------------------------------------------------------
// fused e2f gather (relu + norm; e2fnrm written)
// ---------------------------------------------------------------------------
__global__ __launch_bounds__(256) void gather_fused_e2f_k(
    const int* __restrict__ rowptr, const int* __restrict__ col,
    const float* __restrict__ valp, const float* __restrict__ headsrc,
    const float* __restrict__ pr, const float* __restrict__ sm,
    const float* __restrict__ Wtil, float* __restrict__ e2fnrm,
    float* __restrict__ dst, int nrows)
{
    int gid = blockIdx.x * 256 + threadIdx.x;
    int row = gid >> 6, lane = gid & 63;
    if (row >= nrows) return;
    int b = row / FF;
    const float* prb = pr + (size_t)b * EE;
    const float* smb = sm + (size_t)b * EE;
    float4* dp = (float4*)(dst + (size_t)row * DD + (lane << 2));
    float4 acc = *dp;
    float ns = 0.f;
    int j0 = rowptr[row], j1 = rowptr[row + 1];
    for (int j = j0; j < j1; ++j) {
        int c = col[j];
        float v = valp[j];
        float4 x = *(const float4*)(headsrc + ((size_t)b * EE + c) * DD + (lane << 2));
        acc.x += v * x.x; acc.y += v * x.y; acc.z += v * x.z; acc.w += v * x.w;
        ns += v * (prb[c] / fmaxf(smb[c], VSMALL));
    }
    float nrm = Wtil[row] * ns;
    if (lane == 0) e2fnrm[row] = nrm;
    acc.x = fmaxf(acc.x, 0.f) * nrm; acc.y = fmaxf(acc.y, 0.f) * nrm;
    acc.z = fmaxf(acc.z, 0.f) * nrm; acc.w = fmaxf(acc.w, 0.f) * nrm;
    *dp = acc;
}

// dst[row] = sum val*src[b,c]  (pure gather, fp32 out)
__global__ __launch_bounds__(256) void gather_sum_k(
    const int* __restrict__ rowptr, const int* __restrict__ col,
    const float* __restrict__ valp, const float* __restrict__ src,
    float* __restrict__ dst, int nrows, int nrPerB, int ncs)
{
    int gid = blockIdx.x * 256 + threadIdx.x;
    int row = gid >> 6, lane = gid & 63;
    if (row >= nrows) return;
    int b = row / nrPerB;
    float4 acc = make_float4(0.f, 0.f, 0.f, 0.f);
    int j0 = rowptr[row], j1 = rowptr[row + 1];
    for (int j = j0; j < j1; ++j) {
        int c = col[j];
        float v = valp[j];
        float4 x = *(const float4*)(src + ((size_t)b * ncs + c) * DD + (lane << 2));
        acc.x += v * x.x; acc.y += v * x.y; acc.z += v * x.z; acc.w += v * x.w;
    }
    *(float4*)(dst + (size_t)row * DD + (lane << 2)) = acc;
}

// ---------------------------------------------------------------------------
// LSTM v2 (r12 proven): 64 blocks, Whh LDS-cached, 1 grid barrier/step.
// ---------------------------------------------------------------------------
#define LSTM_BLOCKS 64
__global__ __launch_bounds__(256, 1) void lstm2_k(
    const float* __restrict__ Xg, const float* __restrict__ Whh,
    const float* __restrict__ bhh, float* __restrict__ gbuf,
    unsigned* __restrict__ bar, float* __restrict__ qh, float* __restrict__ qne)
{
    __shared__ float wslice[128 * 257];
    __shared__ float hbuf[256];
    __shared__ float cbuf[256];
    __shared__ float gpart[256];
    const int B = blockIdx.x;
    const int b = B >> 3, p = B & 7;
    const int t = threadIdx.x;
    const float* wsrc = Whh + (size_t)p * 128 * 256;
    for (int i = t; i < 128 * 64; i += 256) {
        int row = i >> 6, q4 = (i & 63) << 2;
        float4 w = *(const float4*)(wsrc + (size_t)row * 256 + q4);
        float* d = &wslice[row * 257 + q4];
        d[0] = w.x; d[1] = w.y; d[2] = w.z; d[3] = w.w;
    }
    hbuf[t] = 0.f; cbuf[t] = 0.f;
    __syncthreads();

    unsigned* bar_cnt = bar;
    unsigned* bar_gen = bar + 1;

    for (int step = 0; step < QQ; ++step) {
        {
            const int r = t & 127, half = t >> 7;
            const float* wr = &wslice[r * 257 + half * 128];
            const float* hb = &hbuf[half * 128];
            float acc = 0.f;
            #pragma unroll 8
            for (int k = 0; k < 128; ++k) acc += wr[k] * hb[k];
            gpart[t] = acc;
        }
        __syncthreads();
        if (t < 128) {
            const int gr = p * 128 + t;
            float g = bhh[gr] + Xg[((size_t)b * QQ + step) * 1024 + gr]
                    + gpart[t] + gpart[t + 128];
            gbuf[((size_t)(step & 1) * BB + b) * 1024 + gr] = g;
        }
        __syncthreads();
        if (t == 0) {
            __threadfence();
            const unsigned target = (unsigned)(step + 1) * LSTM_BLOCKS;
            unsigned old = atomicAdd(bar_cnt, 1u);
            if (old == target - 1u) {
                atomicExch(bar_gen, (unsigned)(step + 1));
            } else {
                while (atomicAdd(bar_gen, 0u) < (unsigned)(step + 1)) {}
            }
            __threadfence();
        }
        __syncthreads();
        {
            const float* g = gbuf + ((size_t)(step & 1) * BB + b) * 1024;
            float gi = g[t], gf = g[256 + t], gg = g[512 + t], go = g[768 + t];
            float si = 1.f / (1.f + expf(-gi));
            float sf = 1.f / (1.f + expf(-gf));
            float so = 1.f / (1.f + expf(-go));
            float c = sf * cbuf[t] + si * tanhf(gg);
            float hh = so * tanhf(c);
            cbuf[t] = c;
            hbuf[t] = hh;
            if (p == 0) qh[((size_t)b * QQ + step) * DD + t] = hh;
        }
        __syncthreads();
    }
    if (p == 0) qne[(size_t)b * DD + t] = hbuf[t];
}

// ---------------------------------------------------------------------------
// sim -> softmax -> Wt ; rowmax+Wtil ; e2f_softmax scatter
// ---------------------------------------------------------------------------
__global__ __launch_bounds__(256) void simwt_k(
    const float* __restrict__ qhid, const int* __restrict__ qtext,
    const float* __restrict__ lfe, float* __restrict__ Wt)
{
    __shared__ float qs[QQ * DD];
    __shared__ float qmn[QQ];
    const int b = blockIdx.y;
    const int f = blockIdx.x * 256 + threadIdx.x;
    for (int i = threadIdx.x; i < QQ * DD; i += 256) qs[i] = qhid[(size_t)b * QQ * DD + i];
    if (threadIdx.x < QQ)
        qmn[threadIdx.x] = (qtext[b * QQ + threadIdx.x] != NWORD) ? 0.f : VNEG;
    __syncthreads();
    if (f >= FF) return;
    float acc[QQ];
    #pragma unroll
    for (int q = 0; q < QQ; ++q) acc[q] = 0.f;
    const float* lr = lfe + ((size_t)b * FF + f) * DD;
    for (int d = 0; d < DD; d += 4) {
        float4 x = *(const float4*)(lr + d);
        #pragma unroll
        for (int q = 0; q < QQ; ++q) {
            float4 y = *(const float4*)&qs[q * DD + d];
            acc[q] += x.x * y.x + x.y * y.y + x.z * y.z + x.w * y.w;
        }
    }
    const float inv = 0.0625f;
    float pre[QQ], m = -INFINITY;
    #pragma unroll
    for (int q = 0; q < QQ; ++q) { pre[q] = acc[q] * inv + qmn[q]; m = fmaxf(m, pre[q]); }
    float s = 0.f;
    #pragma unroll
    for (int q = 0; q < QQ; ++q) s += expf(pre[q] - m);
    float wt = 0.f;
    #pragma unroll
    for (int q = 0; q < QQ; ++q) wt += (expf(pre[q] - m) / s) * (acc[q] * inv);
    Wt[(size_t)b * FF + f] = wt;
}

__global__ __launch_bounds__(256) void rowmax_wtil_k(
    const float* __restrict__ Wt, float* __restrict__ Wtil)
{
    __shared__ float red[256];
    int b = blockIdx.x, t = threadIdx.x;
    float m = -INFINITY;
    for (int f = t; f < FF; f += 256) m = fmaxf(m, Wt[b * FF + f]);
    red[t] = m; __syncthreads();
    for (int s = 128; s > 0; s >>= 1) {
        if (t < s) red[t] = fmaxf(red[t], red[t + s]);
        __syncthreads();
    }
    float mx = red[0];
    for (int f = t; f < FF; f += 256) Wtil[b * FF + f] = expf(Wt[b * FF + f] - mx);
}

__global__ void scatter_sm_k(const int* __restrict__ idx, const float* __restrict__ val,
                             const float* __restrict__ Wtil, float* __restrict__ dst)
{
    int k = blockIdx.x * 256 + threadIdx.x;
    if (k >= NNZ_) return;
    int b = idx[k], e = idx[2 * NNZ_ + k], f = idx[NNZ_ + k];
    atomicAdd(&dst[(size_t)b * EE + e], val[k] * Wtil[(size_t)b * FF + f]);
}

// ---------------------------------------------------------------------------
// initial qlin + ebias (float4 weight loads)
// ---------------------------------------------------------------------------
__global__ __launch_bounds__(256) void qlin_ebias_k(
    const float* __restrict__ qne, const float* __restrict__ q2eW,
    const float* __restrict__ q2eb, const float* __restrict__ e2eW,
    const float* __restrict__ e2eb, float* __restrict__ qlin, float* __restrict__ ebias)
{
    __shared__ float xs[DD], qs[DD];
    int b = blockIdx.x, j = threadIdx.x;
    xs[j] = qne[b * DD + j];
    __syncthreads();
    float acc = q2eb[j];
    const float* wr = q2eW + (size_t)j * DD;
    #pragma unroll 4
    for (int k = 0; k < DD; k += 4) {
        float4 w = *(const float4*)(wr + k);
        acc += xs[k] * w.x + xs[k + 1] * w.y + xs[k + 2] * w.z + xs[k + 3] * w.w;
    }
    qlin[b * DD + j] = acc;
    qs[j] = acc;
    __syncthreads();
    float acc2 = e2eb[j];
    const float* wr2 = e2eW + (size_t)j * 768 + 256;
    #pragma unroll 4
    for (int k = 0; k < DD; k += 4) {
        float4 w = *(const float4*)(wr2 + k);
        acc2 += qs[k] * w.x + qs[k + 1] * w.y + qs[k + 2] * w.z + qs[k + 3] * w.w;
    }
    ebias[b * DD + j] = acc2;
}

// ---------------------------------------------------------------------------
// qne update + next layer's qlin/ebias (float4 weight loads)
// ---------------------------------------------------------------------------
__global__ __launch_bounds__(256) void qneupd_qlin_k(
    const float* __restrict__ vpartL, const float* __restrict__ vpartF,
    const float* __restrict__ vpartS, const float* __restrict__ qlinCur,
    const float* __restrict__ W, const float* __restrict__ bias,
    float* __restrict__ qne,
    const float* __restrict__ q2eWn, const float* __restrict__ q2ebn,
    const float* __restrict__ e2eWn, const float* __restrict__ e2ebn,
    float* __restrict__ qlinNext, float* __restrict__ ebiasNext)
{
    __shared__ float s1[DD], s2[DD], s3[DD], qn[DD], qs[DD];
    int b = blockIdx.x, j = threadIdx.x;
    float a1 = 0.f, a3 = 0.f, sp = 0.f;
    for (int ch = 0; ch < NCHK; ++ch) {
        int pi = ch * BB + b;
        a1 += vpartL[(size_t)pi * DD + j];
        a3 += vpartF[(size_t)pi * DD + j];
        sp += vpartS[pi];
    }
    s1[j] = a1; s2[j] = qlinCur[b * DD + j]; s3[j] = a3;
    __syncthreads();
    float acc = sp * bias[j];
    const float* wr = W + (size_t)j * 768;
    #pragma unroll 4
    for (int k = 0; k < DD; k += 4) {
        float4 w0 = *(const float4*)(wr + k);
        float4 w1 = *(const float4*)(wr + 256 + k);
        float4 w2 = *(const float4*)(wr + 512 + k);
        acc += s1[k] * w0.x + s1[k + 1] * w0.y + s1[k + 2] * w0.z + s1[k + 3] * w0.w;
        acc += sp * (s2[k] * w1.x + s2[k + 1] * w1.y + s2[k + 2] * w1.z + s2[k + 3] * w1.w);
        acc += 3.f * (s3[k] * w2.x + s3[k + 1] * w2.y + s3[k + 2] * w2.z + s3[k + 3] * w2.w);
    }
    qne[b * DD + j] = acc;
    qn[j] = acc;
    __syncthreads();
    float aq = q2ebn[j];
    const float* wq = q2eWn + (size_t)j * DD;
    #pragma unroll 4
    for (int k = 0; k < DD; k += 4) {
        float4 w = *(const float4*)(wq + k);
        aq += qn[k] * w.x + qn[k + 1] * w.y + qn[k + 2] * w.z + qn[k + 3] * w.w;
    }
    qlinNext[b * DD + j] = aq;
    qs[j] = aq;
    __syncthreads();
    float ae = e2ebn[j];
    const float* we = e2eWn + (size_t)j * 768 + 256;
    #pragma unroll 4
    for (int k = 0; k < DD; k += 4) {
        float4 w = *(const float4*)(we + k);
        ae += qs[k] * w.x + qs[k + 1] * w.y + qs[k + 2] * w.z + qs[k + 3] * w.w;
    }
    ebiasNext[b * DD + j] = ae;
}

// ---------------------------------------------------------------------------
// epilogue: partial (64 blocks: 8 batches x 8 row-chunks) + combine.
// Semantics: strict > replaces; ties keep smaller index (== np.argmax).
// ---------------------------------------------------------------------------
__global__ __launch_bounds__(256) void final_part_k(
    const float* __restrict__ lee, const float* __restrict__ sw_,
    const float* __restrict__ sb, const int* __restrict__ local_entity,
    const float* __restrict__ ans, float* __restrict__ out,
    float* __restrict__ fpl, float* __restrict__ fpv, int* __restrict__ fpi)
{
    __shared__ float sw[DD];
    int b = blockIdx.x >> 3, ch = blockIdx.x & 7, t = threadIdx.x;
    sw[t] = sw_[t];
    __syncthreads();
    float sb0 = sb[0];
    float lsum = 0.f, bm = -INFINITY;
    int bi = EE;
    int e0 = ch * 250;
    for (int e = e0 + t; e < e0 + 250; e += 256) {
        const float* a = lee + ((size_t)b * EE + e) * DD;
        float s = sb0;
        for (int k = 0; k < DD; k += 4) {
            float4 v = *(const float4*)(a + k);
            s += v.x * sw[k] + v.y * sw[k + 1] + v.z * sw[k + 2] + v.w * sw[k + 3];
        }
        float mask = (local_entity[b * EE + e] != NENT) ? 1.f : 0.f;
        float smv = s + (1.f - mask) * VNEG;
        float sig;
        if (smv >= 0.f) sig = 1.f / (1.f + expf(-smv));
        else { float es = expf(smv); sig = es / (1.f + es); }
        out[1 + BB + b * EE + e] = sig * mask;
        lsum += fmaxf(s, 0.f) - s * ans[b * EE + e] + log1pf(expf(-fabsf(s)));
        if (smv > bm) { bm = smv; bi = e; }
    }
    __shared__ float rv[256]; __shared__ int ri[256]; __shared__ float rl[256];
    rv[t] = bm; ri[t] = bi; rl[t] = lsum;
    __syncthreads();
    for (int s = 128; s > 0; s >>= 1) {
        if (t < s) {
            rl[t] += rl[t + s];
            if (rv[t + s] > rv[t] || (rv[t + s] == rv[t] && ri[t + s] < ri[t])) {
                rv[t] = rv[t + s]; ri[t] = ri[t + s];
            }
        }
        __syncthreads();
    }
    if (t == 0) { fpl[blockIdx.x] = rl[0]; fpv[blockIdx.x] = rv[0]; fpi[blockIdx.x] = ri[0]; }
}

__global__ void final_combine_k(const float* __restrict__ fpl,
                                const float* __restrict__ fpv,
                                const int* __restrict__ fpi, float* __restrict__ out)
{
    __shared__ float lsums[BB];
    int t = threadIdx.x;
    if (t < BB) {
        float ls = 0.f, bm = -INFINITY;
        int bi = EE;
        for (int ch = 0; ch < 8; ++ch) {
            int i = t * 8 + ch;
            ls += fpl[i];
            if (fpv[i] > bm || (fpv[i] == bm && fpi[i] < bi)) { bm = fpv[i]; bi = fpi[i]; }
        }
        out[1 + t] = (float)bi;
        lsums[t] = ls;
    }
    __syncthreads();
    if (t == 0) {
        float s = 0.f;
        for (int b = 0; b < BB; ++b) s += lsums[b];
        out[0] = s / (float)(BB * EE);
    }
}

// ---------------------------------------------------------------------------
extern "C" void kernel_launch(void* const* d_in, const int* in_sizes, int n_in,
                              void* d_out, int out_size, void* d_ws, size_t ws_size,
                              hipStream_t stream)
{
    (void)in_sizes; (void)n_in; (void)out_size; (void)ws_size;
    const int*   local_entity = (const int*)d_in[0];
    const float* q2e_adj      = (const float*)d_in[1];
    const int*   kb_fact_rel  = (const int*)d_in[2];
    const int*   query_text   = (const int*)d_in[3];
    const float* answer_dist  = (const float*)d_in[4];
    const int*   e2f_idx      = (const int*)d_in[5];
    const float* e2f_val      = (const float*)d_in[6];
    const int*   f2e_idx      = (const int*)d_in[7];
    const float* f2e_val      = (const float*)d_in[8];
    const float* entity_table = (const float*)d_in[9];
    const float* ent_W        = (const float*)d_in[10];
    const float* ent_b        = (const float*)d_in[11];
    const float* rel_table    = (const float*)d_in[12];
    const float* rel_W        = (const float*)d_in[13];
    const float* rel_b        = (const float*)d_in[14];
    const float* word_table   = (const float*)d_in[15];
    const float* Wih          = (const float*)d_in[16];
    const float* Whh          = (const float*)d_in[17];
    const float* bih          = (const float*)d_in[18];
    const float* bhh          = (const float*)d_in[19];
    const float* q2e_W        = (const float*)d_in[20];
    const float* q2e_b        = (const float*)d_in[21];
    const float* e2q_W        = (const float*)d_in[22];
    const float* e2q_b        = (const float*)d_in[23];
    const float* e2e_W        = (const float*)d_in[24];
    const float* e2e_b        = (const float*)d_in[25];
    const float* head_W       = (const float*)d_in[26];
    const float* head_b       = (const float*)d_in[27];
    const float* tail_W       = (const float*)d_in[28];
    const float* tail_b       = (const float*)d_in[29];
    const float* self_W       = (const float*)d_in[30];
    const float* self_b       = (const float*)d_in[31];
    const float* score_W      = (const float*)d_in[32];
    const float* score_b      = (const float*)d_in[33];

    const int NR1 = BB * FF;   // 48000
    const int NR2 = BB * EE;   // 16000

    float* ws = (float*)d_ws;
    size_t off = 0;
    auto alloc = [&](size_t n) { float* p = ws + off; off += n; return p; };
    auto salloc = [&](size_t nshorts) { short* p = (short*)(ws + off); off += (nshorts + 1) / 2; return p; };
    float* Xg      = alloc((size_t)BB * QQ * 1024);
    float* gbuf    = alloc((size_t)2 * BB * 1024);
    float* qh      = alloc((size_t)BB * QQ * DD);
    float* qne     = alloc(BB * DD);
    float* lfe     = alloc((size_t)NR1 * DD);
    float* leeA    = alloc((size_t)NR2 * DD);
    float* leeB    = alloc((size_t)NR2 * DD);
    float* Wt      = alloc(BB * FF);
    float* Wtil    = alloc(BB * FF);
    float* e2fsm   = alloc(BB * EE);
    float* pr      = alloc(BB * EE);
    float* qlinA   = alloc(BB * DD);
    float* qlinB   = alloc(BB * DD);
    float* ebiasA  = alloc(BB * DD);
    float* ebiasB  = alloc(BB * DD);
    float* e2fnrm  = alloc(BB * FF);
    float* fpl     = alloc(64);
    float* fpv     = alloc(64);
    float* bufC    = alloc((size_t)NR2 * DD);
    float* e2fT    = alloc((size_t)NR1 * DD);
    float* f2eT    = alloc((size_t)NR2 * DD);
    float* tmp     = alloc((size_t)NR2 * DD);
    float* vpartL  = alloc((size_t)NCHK * BB * DD);
    float* vpartF  = alloc((size_t)NCHK * BB * DD);
    float* vpartS  = alloc(NCHK * BB);
    float* degw2   = alloc(NR2);
    float* e2f_vp  = alloc(NNZ_);
    float* f2e_vp  = alloc(NNZ_);
    short* wbh     = salloc((size_t)17 * 65536);
    short* wbl     = salloc((size_t)17 * 65536);
    int* ib = (int*)(ws + off);
    size_t ioff = 0;
    auto ialloc = [&](size_t n) { int* p = ib + ioff; ioff += n; return p; };
    int* e2f_cnt = ialloc(NR1);
    int* e2f_rp  = ialloc(NR1 + 1);
    int* e2f_cur = ialloc(NR1);
    int* e2f_col = ialloc(NNZ_);
    int* f2e_cnt = ialloc(NR2);
    int* f2e_rp  = ialloc(NR2 + 1);
    int* f2e_cur = ialloc(NR2);
    int* f2e_col = ialloc(NNZ_);
    int* fpi     = ialloc(64);
    unsigned* bar = (unsigned*)ialloc(2);

    auto WH = [&](int m) { return wbh + (size_t)m * 65536; };
    auto WL = [&](int m) { return wbl + (size_t)m * 65536; };

    float* outp = (float*)d_out;
    const int SCB = (NNZ_ + 255) / 256;

    // ---- prologue: wpack + CSR counts + Xg GEMM, ONE dispatch ----
    hipMemsetAsync(e2f_cnt, 0, NR1 * sizeof(int), stream);
    hipMemsetAsync(f2e_cnt, 0, NR2 * sizeof(int), stream);
    hipMemsetAsync(bar, 0, 2 * sizeof(unsigned), stream);
    prologue_k<<<5126, 256, 0, stream>>>(
        rel_W, ent_W, head_W, tail_W, self_W, e2e_W, wbh, wbl,
        e2f_idx, e2f_cnt, f2e_idx, f2e_cnt,
        word_table, query_text, Wih, bih, Xg);

    // ---- CSR scan + fill + degw ----
    scan2_k<<<2, 1024, 0, stream>>>(e2f_cnt, e2f_rp, e2f_cur, NR1,
                                    f2e_cnt, f2e_rp, f2e_cur, NR2);
    csr_fill2_k<<<dim3(SCB, 2), 256, 0, stream>>>(
        e2f_idx, e2f_val, e2f_cur, e2f_col, e2f_vp,
        f2e_idx, f2e_val, f2e_cur, f2e_col, f2e_vp);
    degw_k<<<(NR2 + 255) / 256, 256, 0, stream>>>(f2e_rp, f2e_vp, degw2, NR2);

    // ---- LSTM recurrence ----
    lstm2_k<<<LSTM_BLOCKS, 256, 0, stream>>>(Xg, Whh, bhh, gbuf, bar, qh, qne);

    // ---- embeddings: rel + ent gathered GEMMs, ONE MFMA dispatch ----
    mgemm_pair_k<1><<<dim3(2, 375 + 125), 256, 0, stream>>>(
        rel_table, kb_fact_rel, WH(0), WL(0), rel_b, lfe, 375,
        entity_table, local_entity, WH(1), WL(1), ent_b, leeA);

    // ---- attention -> W_tilde ----
    simwt_k<<<dim3((FF + 255) / 256, BB), 256, 0, stream>>>(qh, query_text, lfe, Wt);
    rowmax_wtil_k<<<BB, 256, 0, stream>>>(Wt, Wtil);

    // ---- e2f_softmax ----
    hipMemsetAsync(e2fsm, 0, BB * EE * sizeof(float), stream);
    scatter_sm_k<<<SCB, 256, 0, stream>>>(e2f_idx, e2f_val, Wtil, e2fsm);

    // ---- pagerank init + initial qlin/ebias ----
    hipMemcpyAsync(pr, q2e_adj, BB * EE * sizeof(float), hipMemcpyDeviceToDevice, stream);
    qlin_ebias_k<<<BB, 256, 0, stream>>>(qne, q2e_W, q2e_b, e2e_W, e2e_b, qlinA, ebiasA);

    float* lee = leeA;   float* lee2 = leeB;
    float* qlinCur = qlinA;  float* qlinNxt = qlinB;
    float* ebiasCur = ebiasA; float* ebiasNxt = ebiasB;

    for (int i = 0; i < 3; ++i) {
        const float* headbi = head_b + i * DD;
        const float* tailbi = tail_b + i * DD;
        const float* selfbi = self_b + i * DD;

        // head(lee) -> bufC  AND  self(lfe) -> e2fT, one MFMA dispatch
        mgemm_pair_k<0><<<dim3(2, 125 + 375), 256, 0, stream>>>(
            lee, nullptr, WH(2 + i), WL(2 + i), headbi, bufC, 125,
            lfe, nullptr, WH(8 + i), WL(8 + i), selfbi, e2fT);

        // e2fT = relu(e2fT + gather_e2f(bufC)) * nrm ; e2fnrm written
        gather_fused_e2f_k<<<(NR1 * 64) / 256, 256, 0, stream>>>(
            e2f_rp, e2f_col, e2f_vp, bufC, pr, e2fsm, Wtil, e2fnrm, e2fT, NR1);

        // tmp = gather_f2e(e2fT)
        gather_sum_k<<<(NR2 * 64) / 256, 256, 0, stream>>>(
            f2e_rp, f2e_col, f2e_vp, e2fT, tmp, NR2, EE, FF);

        // f2eT = relu(lee@selfW^T + tmp@tailW^T + selfb + degw*tailb)
        mgemm_k<0, 1, 1, 1, 0><<<dim3(2, 125), 256, 0, stream>>>(
            lee, nullptr, tmp, 1.f, WH(8 + i), WL(8 + i), WH(5 + i), WL(5 + i),
            selfbi, degw2, tailbi, f2eT);

        // lee2 GEMM (+ vreduce_pr except last layer), one dispatch
        if (i < 2) {
            tail_k<1><<<450, 256, 0, stream>>>(
                lee, f2eT, WH(11 + i), WL(11 + i), WH(14 + i), WL(14 + i),
                ebiasCur, lee2,
                f2e_rp, f2e_col, f2e_vp, e2fnrm, pr, vpartL, vpartF, vpartS);
            const float* e2qWi = e2q_W + (size_t)i * DD * 3 * DD;
            const float* e2qbi = e2q_b + i * DD;
            const float* q2eWn = q2e_W + (size_t)(i + 1) * DD * DD;
            const float* q2ebn = q2e_b + (i + 1) * DD;
            const float* e2eWn = e2e_W + (size_t)(i + 1) * DD * 3 * DD;
            const float* e2ebn = e2e_b + (i + 1) * DD;
            qneupd_qlin_k<<<BB, 256, 0, stream>>>(
                vpartL, vpartF, vpartS, qlinCur, e2qWi, e2qbi, qne,
                q2eWn, q2ebn, e2eWn, e2ebn, qlinNxt, ebiasNxt);
        } else {
            tail_k<0><<<250, 256, 0, stream>>>(
                lee, f2eT, WH(11 + i), WL(11 + i), WH(14 + i), WL(14 + i),
                ebiasCur, lee2,
                f2e_rp, f2e_col, f2e_vp, e2fnrm, pr, vpartL, vpartF, vpartS);
        }

        // buffer rotation AFTER the last consumer of ebiasCur/lee
        { float* t = lee; lee = lee2; lee2 = t; }
        if (i < 2) {
            { float* t = qlinCur; qlinCur = qlinNxt; qlinNxt = t; }
            { float* t = ebiasCur; ebiasCur = ebiasNxt; ebiasNxt = t; }
        }
    }

    // ---- epilogue: 64-block partials + combine ----
    final_part_k<<<64, 256, 0, stream>>>(lee, score_W, score_b, local_entity,
                                         answer_dist, outp, fpl, fpv, fpi);
    final_combine_k<<<1, 64, 0, stream>>>(fpl, fpv, fpi, outp);
}